// Round 17
// baseline (211.030 us; speedup 1.0000x reference)
//
#include <hip/hip_runtime.h>
#include <hip/hip_bf16.h>

// Problem constants
#define BB 2
#define CC 256
#define HH 96
#define WW 96
#define HWP (HH*WW)        // 9216
#define NTOT (BB*HWP)      // 18432 flattened (b,p)
#define K1 2304            // 256*9, GEMM K for both convs
#define NKT 36             // K1/64 k-steps
#define KHS 18             // k-steps per in-block split-K half (gemm2)

// d_out layout: logits[2,1,96,96], bbox[2,4,96,96], shape[2,2,96,96], loc[2,1,96,96]
#define OUT_LOGITS 0
#define OUT_BBOX   (2*1*HWP)
#define OUT_SHAPE  (OUT_BBOX + 2*4*HWP)
#define OUT_LOC    (OUT_SHAPE + 2*2*HWP)

typedef __attribute__((ext_vector_type(8))) short short8v;   // 8 bf16 (4 VGPRs)
typedef __attribute__((ext_vector_type(4))) float f32x4;

// XCD-aware swizzles: contiguous slab of consecutive n-blocks per XCD.
__device__ __forceinline__ int xcd_swizzle288(int bx) {    // 288 = 8 x 36
    return (bx & 7) * 36 + (bx >> 3);
}
__device__ __forceinline__ int xcd_swizzle576(int bx) {    // 576 = 8 x 72
    return (bx & 7) * 72 + (bx >> 3);
}

__device__ __forceinline__ float bf2f(unsigned short u) {
    return __uint_as_float(((unsigned)u) << 16);
}
__device__ __forceinline__ unsigned short f2bf(float f) {
    unsigned u = __float_as_uint(f);
    u += 0x7FFFu + ((u >> 16) & 1u);           // round-to-nearest-even
    return (unsigned short)(u >> 16);
}

// ------- prep: weights -> bf16 PRE-SWIZZLED A panels + zero page ------------
__global__ __launch_bounds__(256) void prep_kernel(
    const float* __restrict__ conv_w, const float* __restrict__ adapt_w,
    unsigned short* __restrict__ W1p, unsigned short* __restrict__ W2p,
    unsigned short* __restrict__ zp)
{
    const int t = blockIdx.x * 256 + threadIdx.x;
    if (t < 1024) zp[t] = 0;                    // zero page (ws is re-poisoned!)
    if (t < CC * K1) {
        const int e = t & 7;
        {   // W1p
            const int s  = (t >> 3) & 1023;
            const int r  = t >> 13;             // cb*36+kt, [0,72)
            const int kt = r % 36, cb = r / 36;
            const int row = s & 127, kc = s >> 7;
            const int co = cb * 128 + row;
            const int k  = kt * 64 + kc * 8 + e;
            const int kk = k >> 8, ci = k & 255;
            W1p[t] = f2bf(conv_w[co * K1 + ci * 9 + kk]);
        }
        {   // W2p
            const int s  = (t >> 3) & 2047;
            const int kt = t >> 14;             // [0,36)
            const int row = s & 255, kc = s >> 8;
            const int k  = kt * 64 + kc * 8 + e;
            const int kk = k >> 8, ci = k & 255;
            W2p[t] = f2bf(adapt_w[row * K1 + ci * 9 + kk]);
        }
    }
}

// ------------- transpose feature [b][c][p] fp32 -> f_cf [b][p][c] bf16 ------
// R12: store phase vectorized to ushort4 (512 B/wave-instr vs 128 B scalar).
__global__ __launch_bounds__(256) void transpose_kernel(
    const float* __restrict__ f, unsigned short* __restrict__ fcf)
{
    __shared__ unsigned short tile[64][66];     // +2 pad
    const int p0 = blockIdx.x * 64;
    const int cc = blockIdx.y;
    const int b  = blockIdx.z;
    const int tx = threadIdx.x & 63, ty = threadIdx.x >> 6;
#pragma unroll
    for (int ii = 0; ii < 16; ii++) {
        const int cl = ii * 4 + ty;
        tile[cl][tx] = f2bf(f[((size_t)b * CC + cc * 64 + cl) * HWP + p0 + tx]);
    }
    __syncthreads();
    const int tx4 = threadIdx.x & 15;           // c-quad index (c = tx4*4..+3)
    const int py  = threadIdx.x >> 4;           // pixel sub-index (0..15)
#pragma unroll
    for (int ii = 0; ii < 4; ii++) {
        const int pl = ii * 16 + py;
        ushort4 v;
        v.x = tile[tx4 * 4 + 0][pl];
        v.y = tile[tx4 * 4 + 1][pl];
        v.z = tile[tx4 * 4 + 2][pl];
        v.w = tile[tx4 * 4 + 3][pl];
        *(ushort4*)(fcf + ((size_t)(b * HWP + p0 + pl)) * CC + cc * 64 + tx4 * 4) = v;
    }
}

// --------- GEMM1: t = relu(W1 x im2col + bias), 512 thr / 8 waves -----------
// M=128 x N=64, BK=64. R13: cb folded into blockIdx.x (bx&1). K-loop
// R9-exact: A-direct from L2-resident W1p, depth-1 B prefetch.
__global__ __launch_bounds__(512, 6) void gemm1_kernel(
    const unsigned short* __restrict__ W1p, const unsigned short* __restrict__ fcf,
    const float* __restrict__ bias, const unsigned short* __restrict__ zp,
    unsigned short* __restrict__ tcf)
{
    __shared__ short Bs[2][4096];               // 2 x 8 KB (XOR-swizzled)
    const int tid  = threadIdx.x;
    const int lane = tid & 63, w = tid >> 6;    // w in [0,8)
    const int quad = lane >> 4, r15 = lane & 15;
    const int cb  = blockIdx.x & 1;             // interleaved co-half
    const int n0  = xcd_swizzle288(blockIdx.x >> 1) * 64;
    const int co0 = cb * 128;
    const int wm = w & 3, wn = w >> 2;          // co-quarter (32 rows), n-half

    // B staging geometry: thread -> (pixel pr, 8-ch chunk kc)
    const int pr = tid >> 3, kc = tid & 7;
    const int xsw = (pr * 8 + (kc ^ (pr & 7))) * 8;   // Bs write slot (shorts)
    const int nb = n0 + pr;
    const int b  = nb / HWP;
    const int p  = nb - b * HWP;
    const int y = p / WW, x = p % WW;
    const unsigned short* fb = fcf + (size_t)b * HWP * CC;

    f32x4 acc[2][2];
#pragma unroll
    for (int i = 0; i < 2; i++)
#pragma unroll
        for (int j = 0; j < 2; j++) acc[i][j] = (f32x4){0.f, 0.f, 0.f, 0.f};

    auto loadB = [&](int kt) -> short8v {
        const int kk  = kt >> 2;
        const int ci0 = (kt & 3) * 64;
        const int yy = y + kk / 3 - 1, xx = x + kk % 3 - 1;
        const bool ok = (yy >= 0) && (yy < HH) && (xx >= 0) && (xx < WW);
        const unsigned short* src = ok
            ? fb + (size_t)(yy * WW + xx) * CC + ci0 + kc * 8
            : zp;
        return *(const short8v*)src;
    };
    // A-fragment direct from global: slot = kchunk*128 + row within kt-panel.
    auto mma = [&](int buf, int kt) {
        const unsigned short* pnl = W1p + ((size_t)(cb * 36 + kt) * 1024) * 8;
#pragma unroll
        for (int ks = 0; ks < 2; ks++) {
            short8v a[2], bf[2];
            const int kchunk = ks * 4 + quad;
#pragma unroll
            for (int i = 0; i < 2; i++)
                a[i] = *(const short8v*)(pnl + (size_t)(kchunk * 128 + wm * 32 + i * 16 + r15) * 8);
#pragma unroll
            for (int j = 0; j < 2; j++) {
                const int row = wn * 32 + j * 16 + r15;
                bf[j] = *(const short8v*)&Bs[buf][(row * 8 + (kchunk ^ (row & 7))) * 8];
            }
#pragma unroll
            for (int i = 0; i < 2; i++)
#pragma unroll
                for (int j = 0; j < 2; j++)
                    acc[i][j] = __builtin_amdgcn_mfma_f32_16x16x32_bf16(a[i], bf[j], acc[i][j], 0, 0, 0);
        }
    };

    { short8v b0 = loadB(0); *(short8v*)&Bs[0][xsw] = b0; }
    __syncthreads();
    int cur = 0;
    for (int kt = 0; kt < NKT - 1; kt++) {
        const int nxt = cur ^ 1;
        short8v bn = loadB(kt + 1);             // -> regs, latency under MFMA
        mma(cur, kt);
        *(short8v*)&Bs[nxt][xsw] = bn;
        __syncthreads();
        cur = nxt;
    }
    mma(cur, NKT - 1);                          // peeled last tile

    // epilogue: bias + relu -> t_cf[n][c] bf16 (C/D map: col=lane&15, row=quad*4+reg)
#pragma unroll
    for (int i = 0; i < 2; i++) {
        const int m = co0 + wm * 32 + i * 16 + quad * 4;
        const float b0 = bias[m], b1 = bias[m + 1], b2 = bias[m + 2], b3 = bias[m + 3];
#pragma unroll
        for (int j = 0; j < 2; j++) {
            const int n = n0 + wn * 32 + j * 16 + r15;
            ushort4 st;
            st.x = f2bf(fmaxf(acc[i][j][0] + b0, 0.f));
            st.y = f2bf(fmaxf(acc[i][j][1] + b1, 0.f));
            st.z = f2bf(fmaxf(acc[i][j][2] + b2, 0.f));
            st.w = f2bf(fmaxf(acc[i][j][3] + b3, 0.f));
            *(ushort4*)(tcf + (size_t)n * CC + m) = st;
        }
    }
}

// ---- heads1: wave-per-pixel, lane = 4-channel chunk (coalesced row read) ---
__global__ __launch_bounds__(256) void heads1_kernel(
    const unsigned short* __restrict__ tcf,
    const float* __restrict__ loc_w, const float* __restrict__ loc_b,
    const float* __restrict__ shape_w, const float* __restrict__ shape_b,
    float* __restrict__ out, float* __restrict__ s0s1)
{
    const int lane = threadIdx.x & 63, wv = threadIdx.x >> 6;
    const int n = blockIdx.x * 4 + wv;
    const int b = n / HWP, p = n - b * HWP;
    const int c = lane * 4;
    const ushort4 v = *(const ushort4*)(tcf + (size_t)n * CC + c);
    const float f0 = bf2f(v.x), f1 = bf2f(v.y), f2 = bf2f(v.z), f3 = bf2f(v.w);
    float aloc, s0, s1;
    aloc = loc_w[c] * f0;           aloc = fmaf(loc_w[c+1], f1, aloc);
    aloc = fmaf(loc_w[c+2], f2, aloc); aloc = fmaf(loc_w[c+3], f3, aloc);
    s0 = shape_w[c] * f0;           s0 = fmaf(shape_w[c+1], f1, s0);
    s0 = fmaf(shape_w[c+2], f2, s0);   s0 = fmaf(shape_w[c+3], f3, s0);
    s1 = shape_w[CC+c] * f0;        s1 = fmaf(shape_w[CC+c+1], f1, s1);
    s1 = fmaf(shape_w[CC+c+2], f2, s1); s1 = fmaf(shape_w[CC+c+3], f3, s1);
#pragma unroll
    for (int off = 32; off; off >>= 1) {
        aloc += __shfl_xor(aloc, off);
        s0   += __shfl_xor(s0, off);
        s1   += __shfl_xor(s1, off);
    }
    if (lane == 0) {
        const float l = aloc + loc_b[0], a = s0 + shape_b[0], cc2 = s1 + shape_b[1];
        out[OUT_LOC + n] = l;
        out[OUT_SHAPE + (b * 2 + 0) * HWP + p] = a;
        out[OUT_SHAPE + (b * 2 + 1) * HWP + p] = cc2;
        *(float2*)&s0s1[2 * n] = make_float2(a, cc2);
    }
}

// ---- fused GEMM2 + heads, IN-BLOCK split-K, M=256 x N=32, 512 thr ----------
// R17: waves 0-3 process kt 0-17, waves 4-7 process kt 18-35 (disjoint ->
// no duplicated sampler work, NO pta traffic). 8 waves/block -> 18 waves/CU
// (2x R16's TLP; R9's proven lever without its HBM cost). Each group has
// its own Bs half + sampler threads; one block-wide barrier per step.
// Epilogue: fold kh=1 acc into kh=0 via LDS (fp32 add = R9 order), then
// R14-proven fused-heads reduce on waves 0-3.
__global__ __launch_bounds__(512, 4) void gemm2_fused_kernel(
    const unsigned short* __restrict__ W2p, const unsigned short* __restrict__ tcf,
    const float* __restrict__ s0s1, const float* __restrict__ offset_w,
    const float* __restrict__ cls_w, const float* __restrict__ cls_b,
    const float* __restrict__ bbox_w, const float* __restrict__ bbox_b,
    float* __restrict__ out)
{
    __shared__ short Bs[2][2][2048];            // [buf][kh][32 rows x 8 chunks] 16 KB
    __shared__ float xch[4][64][32];            // kh=1 acc exchange, 32 KB
    __shared__ float sm[4][32][6];              // heads reduce, 3 KB
    const int tid  = threadIdx.x;
    const int lane = tid & 63, w8 = tid >> 6;   // 8 waves
    const int kh   = w8 >> 2;                   // wave group: 0 -> kt 0-17, 1 -> 18-35
    const int wm   = w8 & 3;                    // co-quarter (64 rows)
    const int quad = lane >> 4, r15 = lane & 15;
    const int n0  = xcd_swizzle576(blockIdx.x) * 32;
    const int b   = n0 / HWP;                   // whole block in one batch
    const unsigned short* tb = tcf + (size_t)b * HWP * CC;

    // sampler mapping: tid&255 -> pixel pr (0..31), 8-ch chunk kc; group kh
    // samples its own kt range (tid>>8 == kh by construction).
    const int pr = (tid >> 3) & 31, kc = tid & 7;
    const int xsw = (pr * 8 + (kc ^ (pr & 7))) * 8;   // Bs write slot (shorts)
    const int nb = n0 + pr;
    const int p  = nb - b * HWP;
    const int y = p / WW, x = p % WW;
    const float2 s01 = *(const float2*)&s0s1[2 * nb];

    f32x4 acc[4][2];
#pragma unroll
    for (int i = 0; i < 4; i++)
#pragma unroll
        for (int j = 0; j < 2; j++) acc[i][j] = (f32x4){0.f, 0.f, 0.f, 0.f};

    struct Samp { short8v v00, v01, v10, v11; float w00, w01, w10, w11; };

    // issue phase: address math + 4 gathers into regs (R9-verbatim per-pixel math)
    auto sampIssue = [&](int kt) -> Samp {
        Samp s;
        const int kk = kt >> 2, g = kt & 3;
        const int o_dy = (g * 9 + kk) * 2, o_dx = o_dy + 1;
        const float dy = fmaf(offset_w[o_dy * 2], s01.x, offset_w[o_dy * 2 + 1] * s01.y);
        const float dx = fmaf(offset_w[o_dx * 2], s01.x, offset_w[o_dx * 2 + 1] * s01.y);
        const float py = (float)(y + kk / 3 - 1) + dy;
        const float px = (float)(x + kk % 3 - 1) + dx;
        const float y0f = floorf(py), x0f = floorf(px);
        const float wy = py - y0f, wx = px - x0f;
        const int y0 = (int)y0f, x0 = (int)x0f;
        const int y1 = y0 + 1, x1 = x0 + 1;
        const bool vy0 = (y0 >= 0) && (y0 < HH), vy1 = (y1 >= 0) && (y1 < HH);
        const bool vx0 = (x0 >= 0) && (x0 < WW), vx1 = (x1 >= 0) && (x1 < WW);
        const int y0c = min(max(y0, 0), HH - 1), y1c = min(max(y1, 0), HH - 1);
        const int x0c = min(max(x0, 0), WW - 1), x1c = min(max(x1, 0), WW - 1);
        s.w00 = (vy0 && vx0) ? (1.f - wy) * (1.f - wx) : 0.f;
        s.w01 = (vy0 && vx1) ? (1.f - wy) * wx         : 0.f;
        s.w10 = (vy1 && vx0) ? wy * (1.f - wx)         : 0.f;
        s.w11 = (vy1 && vx1) ? wy * wx                 : 0.f;
        const int ch = g * 64 + kc * 8;
        s.v00 = *(const short8v*)(tb + (size_t)(y0c * WW + x0c) * CC + ch);
        s.v01 = *(const short8v*)(tb + (size_t)(y0c * WW + x1c) * CC + ch);
        s.v10 = *(const short8v*)(tb + (size_t)(y1c * WW + x0c) * CC + ch);
        s.v11 = *(const short8v*)(tb + (size_t)(y1c * WW + x1c) * CC + ch);
        return s;
    };
    // finish phase: bilinear blend + bf16 round + swizzled ds_write (own kh half)
    auto sampFinish = [&](const Samp& s, int buf) {
        short8v r;
#pragma unroll
        for (int e = 0; e < 8; e++) {
            float val = s.w00 * bf2f((unsigned short)s.v00[e]);
            val = fmaf(s.w01, bf2f((unsigned short)s.v01[e]), val);
            val = fmaf(s.w10, bf2f((unsigned short)s.v10[e]), val);
            val = fmaf(s.w11, bf2f((unsigned short)s.v11[e]), val);
            r[e] = (short)f2bf(val);
        }
        *(short8v*)&Bs[buf][kh][xsw] = r;
    };
    // A-fragment direct from L2-resident panel; 16 MFMA/wave/kt (own kh half).
    auto mma = [&](int buf, int kt) {
        const unsigned short* pnl = W2p + ((size_t)kt * 2048) * 8;
#pragma unroll
        for (int ks = 0; ks < 2; ks++) {
            short8v a[4], bf[2];
            const int kchunk = ks * 4 + quad;
#pragma unroll
            for (int i = 0; i < 4; i++)
                a[i] = *(const short8v*)(pnl + (size_t)(kchunk * 256 + wm * 64 + i * 16 + r15) * 8);
#pragma unroll
            for (int j = 0; j < 2; j++) {
                const int row = j * 16 + r15;
                bf[j] = *(const short8v*)&Bs[buf][kh][(row * 8 + (kchunk ^ (row & 7))) * 8];
            }
#pragma unroll
            for (int i = 0; i < 4; i++)
#pragma unroll
                for (int j = 0; j < 2; j++)
                    acc[i][j] = __builtin_amdgcn_mfma_f32_16x16x32_bf16(a[i], bf[j], acc[i][j], 0, 0, 0);
        }
    };

    // ---- K-loop: 18 steps, both groups in parallel, one barrier/step ----
    const int kt0 = kh * KHS;
    { Samp s = sampIssue(kt0); sampFinish(s, 0); }
    __syncthreads();
    int cur = 0;
    for (int st = 0; st < KHS - 1; st++) {      // 17 iterations
        const int nxt = cur ^ 1;
        Samp s = sampIssue(kt0 + st + 1);       // gathers in flight over MFMA
        mma(cur, kt0 + st);
        sampFinish(s, nxt);
        __syncthreads();
        cur = nxt;
    }
    mma(cur, kt0 + KHS - 1);                    // peeled last step

    // ---- fold kh=1 partials into kh=0 (fp32 add, R9/heads2 order) ----
    __syncthreads();                            // all mma reads of Bs done
    if (kh == 1) {
#pragma unroll
        for (int i = 0; i < 4; i++)
#pragma unroll
            for (int j = 0; j < 2; j++)
#pragma unroll
                for (int e = 0; e < 4; e++)
                    xch[wm][lane][i * 8 + j * 4 + e] = acc[i][j][e];
    }
    __syncthreads();
    if (kh == 0) {
#pragma unroll
        for (int i = 0; i < 4; i++)
#pragma unroll
            for (int j = 0; j < 2; j++)
#pragma unroll
                for (int e = 0; e < 4; e++)
                    acc[i][j][e] += xch[wm][lane][i * 8 + j * 4 + e];
    }

    // ---- fused epilogue on waves 0-3: relu + cls/bbox dots (R14-exact) ----
    if (kh == 0) {
        float pc[2]  = {0.f, 0.f};
        float pb0[2] = {0.f, 0.f}, pb1[2] = {0.f, 0.f};
        float pb2[2] = {0.f, 0.f}, pb3[2] = {0.f, 0.f};
#pragma unroll
        for (int i = 0; i < 4; i++) {
            const int m = wm * 64 + i * 16 + quad * 4;
            const float4 cw  = *(const float4*)(cls_w + m);
            const float4 b0w = *(const float4*)(bbox_w + m);
            const float4 b1w = *(const float4*)(bbox_w + CC + m);
            const float4 b2w = *(const float4*)(bbox_w + 2 * CC + m);
            const float4 b3w = *(const float4*)(bbox_w + 3 * CC + m);
#pragma unroll
            for (int j = 0; j < 2; j++) {
                const float t0 = fmaxf(acc[i][j][0], 0.f);
                const float t1 = fmaxf(acc[i][j][1], 0.f);
                const float t2 = fmaxf(acc[i][j][2], 0.f);
                const float t3 = fmaxf(acc[i][j][3], 0.f);
                pc[j]  = fmaf(cw.x,  t0, fmaf(cw.y,  t1, fmaf(cw.z,  t2, fmaf(cw.w,  t3, pc[j]))));
                pb0[j] = fmaf(b0w.x, t0, fmaf(b0w.y, t1, fmaf(b0w.z, t2, fmaf(b0w.w, t3, pb0[j]))));
                pb1[j] = fmaf(b1w.x, t0, fmaf(b1w.y, t1, fmaf(b1w.z, t2, fmaf(b1w.w, t3, pb1[j]))));
                pb2[j] = fmaf(b2w.x, t0, fmaf(b2w.y, t1, fmaf(b2w.z, t2, fmaf(b2w.w, t3, pb2[j]))));
                pb3[j] = fmaf(b3w.x, t0, fmaf(b3w.y, t1, fmaf(b3w.z, t2, fmaf(b3w.w, t3, pb3[j]))));
            }
        }
#pragma unroll
        for (int j = 0; j < 2; j++) {
#pragma unroll
            for (int off = 16; off <= 32; off <<= 1) {
                pc[j]  += __shfl_xor(pc[j],  off);
                pb0[j] += __shfl_xor(pb0[j], off);
                pb1[j] += __shfl_xor(pb1[j], off);
                pb2[j] += __shfl_xor(pb2[j], off);
                pb3[j] += __shfl_xor(pb3[j], off);
            }
        }
        if (quad == 0) {                        // lanes 0..15 hold reduced vals
#pragma unroll
            for (int j = 0; j < 2; j++) {
                const int nl = j * 16 + r15;
                sm[wm][nl][0] = pc[j];
                sm[wm][nl][1] = pb0[j];
                sm[wm][nl][2] = pb1[j];
                sm[wm][nl][3] = pb2[j];
                sm[wm][nl][4] = pb3[j];
            }
        }
    }
    __syncthreads();
    if (tid < 32) {                             // one thread per pixel
        const int n = n0 + tid;
        const int bb = n / HWP, pp = n - bb * HWP;
        const float vc = sm[0][tid][0] + sm[1][tid][0] + sm[2][tid][0] + sm[3][tid][0];
        const float v0 = sm[0][tid][1] + sm[1][tid][1] + sm[2][tid][1] + sm[3][tid][1];
        const float v1 = sm[0][tid][2] + sm[1][tid][2] + sm[2][tid][2] + sm[3][tid][2];
        const float v2 = sm[0][tid][3] + sm[1][tid][3] + sm[2][tid][3] + sm[3][tid][3];
        const float v3 = sm[0][tid][4] + sm[1][tid][4] + sm[2][tid][4] + sm[3][tid][4];
        out[OUT_LOGITS + n] = vc + cls_b[0];
        out[OUT_BBOX + (bb * 4 + 0) * HWP + pp] = v0 + bbox_b[0];
        out[OUT_BBOX + (bb * 4 + 1) * HWP + pp] = v1 + bbox_b[1];
        out[OUT_BBOX + (bb * 4 + 2) * HWP + pp] = v2 + bbox_b[2];
        out[OUT_BBOX + (bb * 4 + 3) * HWP + pp] = v3 + bbox_b[3];
    }
}

// ----------------------------------------------------------------------------
extern "C" void kernel_launch(void* const* d_in, const int* in_sizes, int n_in,
                              void* d_out, int out_size, void* d_ws, size_t ws_size,
                              hipStream_t stream)
{
    const float* feature  = (const float*)d_in[0];
    const float* conv_w   = (const float*)d_in[1];
    const float* conv_b   = (const float*)d_in[2];
    const float* loc_w    = (const float*)d_in[3];
    const float* loc_b    = (const float*)d_in[4];
    const float* shape_w  = (const float*)d_in[5];
    const float* shape_b  = (const float*)d_in[6];
    const float* offset_w = (const float*)d_in[7];
    const float* adapt_w  = (const float*)d_in[8];
    const float* cls_w    = (const float*)d_in[9];
    const float* cls_b    = (const float*)d_in[10];
    const float* bbox_w   = (const float*)d_in[11];
    const float* bbox_b   = (const float*)d_in[12];
    float* out = (float*)d_out;

    // workspace partition (~22 MB)
    float*          s0s1 = (float*)d_ws;                           // NTOT float2
    unsigned short* tcf  = (unsigned short*)(s0s1 + 2 * NTOT);     // NTOT*CC bf16
    unsigned short* fcf  = tcf + (size_t)NTOT * CC;                // NTOT*CC bf16
    unsigned short* W1p  = fcf + (size_t)NTOT * CC;                // CC*K1 bf16 (panels)
    unsigned short* W2p  = W1p + (size_t)CC * K1;                  // CC*K1 bf16 (panels)
    unsigned short* zp   = W2p + (size_t)CC * K1;                  // 1024 zeros

    prep_kernel<<<(CC * K1 + 255) / 256, 256, 0, stream>>>(conv_w, adapt_w, W1p, W2p, zp);
    transpose_kernel<<<dim3(HWP / 64, 4, BB), 256, 0, stream>>>(feature, fcf);
    gemm1_kernel<<<dim3(NTOT / 64 * 2), 512, 0, stream>>>(W1p, fcf, conv_b, zp, tcf);
    heads1_kernel<<<dim3(NTOT / 4), 256, 0, stream>>>(
        tcf, loc_w, loc_b, shape_w, shape_b, out, s0s1);
    gemm2_fused_kernel<<<dim3(NTOT / 32), 512, 0, stream>>>(
        W2p, tcf, s0s1, offset_w, cls_w, cls_b, bbox_w, bbox_b, out);
}

// Round 18
// 196.315 us; speedup vs baseline: 1.0750x; 1.0750x over previous
//
#include <hip/hip_runtime.h>
#include <hip/hip_bf16.h>

// Problem constants
#define BB 2
#define CC 256
#define HH 96
#define WW 96
#define HWP (HH*WW)        // 9216
#define NTOT (BB*HWP)      // 18432 flattened (b,p)
#define K1 2304            // 256*9, GEMM K for both convs
#define NKT 36             // K1/64 k-steps

// d_out layout: logits[2,1,96,96], bbox[2,4,96,96], shape[2,2,96,96], loc[2,1,96,96]
#define OUT_LOGITS 0
#define OUT_BBOX   (2*1*HWP)
#define OUT_SHAPE  (OUT_BBOX + 2*4*HWP)
#define OUT_LOC    (OUT_SHAPE + 2*2*HWP)

typedef __attribute__((ext_vector_type(8))) short short8v;   // 8 bf16 (4 VGPRs)
typedef __attribute__((ext_vector_type(4))) float f32x4;

// XCD-aware swizzles: contiguous slab of consecutive n-blocks per XCD.
__device__ __forceinline__ int xcd_swizzle288(int bx) {    // 288 = 8 x 36
    return (bx & 7) * 36 + (bx >> 3);
}
__device__ __forceinline__ int xcd_swizzle576(int bx) {    // 576 = 8 x 72
    return (bx & 7) * 72 + (bx >> 3);
}

__device__ __forceinline__ float bf2f(unsigned short u) {
    return __uint_as_float(((unsigned)u) << 16);
}
__device__ __forceinline__ unsigned short f2bf(float f) {
    unsigned u = __float_as_uint(f);
    u += 0x7FFFu + ((u >> 16) & 1u);           // round-to-nearest-even
    return (unsigned short)(u >> 16);
}

// ------- prep: weights -> bf16 PRE-SWIZZLED A panels + zero page ------------
__global__ __launch_bounds__(256) void prep_kernel(
    const float* __restrict__ conv_w, const float* __restrict__ adapt_w,
    unsigned short* __restrict__ W1p, unsigned short* __restrict__ W2p,
    unsigned short* __restrict__ zp)
{
    const int t = blockIdx.x * 256 + threadIdx.x;
    if (t < 1024) zp[t] = 0;                    // zero page (ws is re-poisoned!)
    if (t < CC * K1) {
        const int e = t & 7;
        {   // W1p
            const int s  = (t >> 3) & 1023;
            const int r  = t >> 13;             // cb*36+kt, [0,72)
            const int kt = r % 36, cb = r / 36;
            const int row = s & 127, kc = s >> 7;
            const int co = cb * 128 + row;
            const int k  = kt * 64 + kc * 8 + e;
            const int kk = k >> 8, ci = k & 255;
            W1p[t] = f2bf(conv_w[co * K1 + ci * 9 + kk]);
        }
        {   // W2p
            const int s  = (t >> 3) & 2047;
            const int kt = t >> 14;             // [0,36)
            const int row = s & 255, kc = s >> 8;
            const int k  = kt * 64 + kc * 8 + e;
            const int kk = k >> 8, ci = k & 255;
            W2p[t] = f2bf(adapt_w[row * K1 + ci * 9 + kk]);
        }
    }
}

// ------------- transpose feature [b][c][p] fp32 -> f_cf [b][p][c] bf16 ------
// R12: store phase vectorized to ushort4 (512 B/wave-instr vs 128 B scalar).
__global__ __launch_bounds__(256) void transpose_kernel(
    const float* __restrict__ f, unsigned short* __restrict__ fcf)
{
    __shared__ unsigned short tile[64][66];     // +2 pad
    const int p0 = blockIdx.x * 64;
    const int cc = blockIdx.y;
    const int b  = blockIdx.z;
    const int tx = threadIdx.x & 63, ty = threadIdx.x >> 6;
#pragma unroll
    for (int ii = 0; ii < 16; ii++) {
        const int cl = ii * 4 + ty;
        tile[cl][tx] = f2bf(f[((size_t)b * CC + cc * 64 + cl) * HWP + p0 + tx]);
    }
    __syncthreads();
    const int tx4 = threadIdx.x & 15;           // c-quad index (c = tx4*4..+3)
    const int py  = threadIdx.x >> 4;           // pixel sub-index (0..15)
#pragma unroll
    for (int ii = 0; ii < 4; ii++) {
        const int pl = ii * 16 + py;
        ushort4 v;
        v.x = tile[tx4 * 4 + 0][pl];
        v.y = tile[tx4 * 4 + 1][pl];
        v.z = tile[tx4 * 4 + 2][pl];
        v.w = tile[tx4 * 4 + 3][pl];
        *(ushort4*)(fcf + ((size_t)(b * HWP + p0 + pl)) * CC + cc * 64 + tx4 * 4) = v;
    }
}

// --------- GEMM1: t = relu(W1 x im2col + bias), 512 thr / 8 waves -----------
// M=128 x N=64, BK=64. R13: cb folded into blockIdx.x (bx&1). K-loop
// R9-exact: A-direct from L2-resident W1p, depth-1 B prefetch.
__global__ __launch_bounds__(512, 6) void gemm1_kernel(
    const unsigned short* __restrict__ W1p, const unsigned short* __restrict__ fcf,
    const float* __restrict__ bias, const unsigned short* __restrict__ zp,
    unsigned short* __restrict__ tcf)
{
    __shared__ short Bs[2][4096];               // 2 x 8 KB (XOR-swizzled)
    const int tid  = threadIdx.x;
    const int lane = tid & 63, w = tid >> 6;    // w in [0,8)
    const int quad = lane >> 4, r15 = lane & 15;
    const int cb  = blockIdx.x & 1;             // interleaved co-half
    const int n0  = xcd_swizzle288(blockIdx.x >> 1) * 64;
    const int co0 = cb * 128;
    const int wm = w & 3, wn = w >> 2;          // co-quarter (32 rows), n-half

    // B staging geometry: thread -> (pixel pr, 8-ch chunk kc)
    const int pr = tid >> 3, kc = tid & 7;
    const int xsw = (pr * 8 + (kc ^ (pr & 7))) * 8;   // Bs write slot (shorts)
    const int nb = n0 + pr;
    const int b  = nb / HWP;
    const int p  = nb - b * HWP;
    const int y = p / WW, x = p % WW;
    const unsigned short* fb = fcf + (size_t)b * HWP * CC;

    f32x4 acc[2][2];
#pragma unroll
    for (int i = 0; i < 2; i++)
#pragma unroll
        for (int j = 0; j < 2; j++) acc[i][j] = (f32x4){0.f, 0.f, 0.f, 0.f};

    auto loadB = [&](int kt) -> short8v {
        const int kk  = kt >> 2;
        const int ci0 = (kt & 3) * 64;
        const int yy = y + kk / 3 - 1, xx = x + kk % 3 - 1;
        const bool ok = (yy >= 0) && (yy < HH) && (xx >= 0) && (xx < WW);
        const unsigned short* src = ok
            ? fb + (size_t)(yy * WW + xx) * CC + ci0 + kc * 8
            : zp;
        return *(const short8v*)src;
    };
    // A-fragment direct from global: slot = kchunk*128 + row within kt-panel.
    auto mma = [&](int buf, int kt) {
        const unsigned short* pnl = W1p + ((size_t)(cb * 36 + kt) * 1024) * 8;
#pragma unroll
        for (int ks = 0; ks < 2; ks++) {
            short8v a[2], bf[2];
            const int kchunk = ks * 4 + quad;
#pragma unroll
            for (int i = 0; i < 2; i++)
                a[i] = *(const short8v*)(pnl + (size_t)(kchunk * 128 + wm * 32 + i * 16 + r15) * 8);
#pragma unroll
            for (int j = 0; j < 2; j++) {
                const int row = wn * 32 + j * 16 + r15;
                bf[j] = *(const short8v*)&Bs[buf][(row * 8 + (kchunk ^ (row & 7))) * 8];
            }
#pragma unroll
            for (int i = 0; i < 2; i++)
#pragma unroll
                for (int j = 0; j < 2; j++)
                    acc[i][j] = __builtin_amdgcn_mfma_f32_16x16x32_bf16(a[i], bf[j], acc[i][j], 0, 0, 0);
        }
    };

    { short8v b0 = loadB(0); *(short8v*)&Bs[0][xsw] = b0; }
    __syncthreads();
    int cur = 0;
    for (int kt = 0; kt < NKT - 1; kt++) {
        const int nxt = cur ^ 1;
        short8v bn = loadB(kt + 1);             // -> regs, latency under MFMA
        mma(cur, kt);
        *(short8v*)&Bs[nxt][xsw] = bn;
        __syncthreads();
        cur = nxt;
    }
    mma(cur, NKT - 1);                          // peeled last tile

    // epilogue: bias + relu -> t_cf[n][c] bf16 (C/D map: col=lane&15, row=quad*4+reg)
#pragma unroll
    for (int i = 0; i < 2; i++) {
        const int m = co0 + wm * 32 + i * 16 + quad * 4;
        const float b0 = bias[m], b1 = bias[m + 1], b2 = bias[m + 2], b3 = bias[m + 3];
#pragma unroll
        for (int j = 0; j < 2; j++) {
            const int n = n0 + wn * 32 + j * 16 + r15;
            ushort4 st;
            st.x = f2bf(fmaxf(acc[i][j][0] + b0, 0.f));
            st.y = f2bf(fmaxf(acc[i][j][1] + b1, 0.f));
            st.z = f2bf(fmaxf(acc[i][j][2] + b2, 0.f));
            st.w = f2bf(fmaxf(acc[i][j][3] + b3, 0.f));
            *(ushort4*)(tcf + (size_t)n * CC + m) = st;
        }
    }
}

// ---- heads1: wave-per-pixel, lane = 4-channel chunk (coalesced row read) ---
__global__ __launch_bounds__(256) void heads1_kernel(
    const unsigned short* __restrict__ tcf,
    const float* __restrict__ loc_w, const float* __restrict__ loc_b,
    const float* __restrict__ shape_w, const float* __restrict__ shape_b,
    float* __restrict__ out, float* __restrict__ s0s1)
{
    const int lane = threadIdx.x & 63, wv = threadIdx.x >> 6;
    const int n = blockIdx.x * 4 + wv;
    const int b = n / HWP, p = n - b * HWP;
    const int c = lane * 4;
    const ushort4 v = *(const ushort4*)(tcf + (size_t)n * CC + c);
    const float f0 = bf2f(v.x), f1 = bf2f(v.y), f2 = bf2f(v.z), f3 = bf2f(v.w);
    float aloc, s0, s1;
    aloc = loc_w[c] * f0;           aloc = fmaf(loc_w[c+1], f1, aloc);
    aloc = fmaf(loc_w[c+2], f2, aloc); aloc = fmaf(loc_w[c+3], f3, aloc);
    s0 = shape_w[c] * f0;           s0 = fmaf(shape_w[c+1], f1, s0);
    s0 = fmaf(shape_w[c+2], f2, s0);   s0 = fmaf(shape_w[c+3], f3, s0);
    s1 = shape_w[CC+c] * f0;        s1 = fmaf(shape_w[CC+c+1], f1, s1);
    s1 = fmaf(shape_w[CC+c+2], f2, s1); s1 = fmaf(shape_w[CC+c+3], f3, s1);
#pragma unroll
    for (int off = 32; off; off >>= 1) {
        aloc += __shfl_xor(aloc, off);
        s0   += __shfl_xor(s0, off);
        s1   += __shfl_xor(s1, off);
    }
    if (lane == 0) {
        const float l = aloc + loc_b[0], a = s0 + shape_b[0], cc2 = s1 + shape_b[1];
        out[OUT_LOC + n] = l;
        out[OUT_SHAPE + (b * 2 + 0) * HWP + p] = a;
        out[OUT_SHAPE + (b * 2 + 1) * HWP + p] = cc2;
        *(float2*)&s0s1[2 * n] = make_float2(a, cc2);
    }
}

// ---- fused GEMM2 + heads2, FULL-K, M=256 x N=32, 256 thr / 4 waves ---------
// R14 (best: 192.6 us): split-K removed; each block holds the COMPLETE
// 256-ch ta for its 32 pixels in registers, so cls/bbox heads fuse into the
// epilogue (relu in-reg -> per-thread 16-ch partial dots -> quad-shuffle ->
// LDS cross-wave reduce -> 6 floats/pixel). Eliminates pta (36.9 MB write)
// and heads2 (73.7 MB read). K-loop: A-reg-prefetch (named-member struct,
// R11-proven), depth-1 sampler, one __syncthreads per kt.
__global__ __launch_bounds__(256, 3) void gemm2_fused_kernel(
    const unsigned short* __restrict__ W2p, const unsigned short* __restrict__ tcf,
    const float* __restrict__ s0s1, const float* __restrict__ offset_w,
    const float* __restrict__ cls_w, const float* __restrict__ cls_b,
    const float* __restrict__ bbox_w, const float* __restrict__ bbox_b,
    float* __restrict__ out)
{
    __shared__ short Bs[2][2048];               // 2 x 4 KB (32 rows x 8 chunks, XOR)
    __shared__ float sm[4][32][6];              // [wave][n][5 heads], +1 pad
    const int tid  = threadIdx.x;
    const int lane = tid & 63, wm = tid >> 6;   // 4 waves, wm = co-quarter (64 rows)
    const int quad = lane >> 4, r15 = lane & 15;
    const int n0  = xcd_swizzle576(blockIdx.x) * 32;
    const int b   = n0 / HWP;                   // whole block in one batch
    const unsigned short* tb = tcf + (size_t)b * HWP * CC;

    // sampler mapping: thread -> pixel pr (0..31), 8-ch chunk kc (one px/thread)
    const int pr = tid >> 3, kc = tid & 7;
    const int xsw = (pr * 8 + (kc ^ (pr & 7))) * 8;   // Bs write slot (shorts)
    const int nb = n0 + pr;
    const int p  = nb - b * HWP;
    const int y = p / WW, x = p % WW;
    const float2 s01 = *(const float2*)&s0s1[2 * nb];

    f32x4 acc[4][2];
#pragma unroll
    for (int i = 0; i < 4; i++)
#pragma unroll
        for (int j = 0; j < 2; j++) acc[i][j] = (f32x4){0.f, 0.f, 0.f, 0.f};

    struct Samp { short8v v00, v01, v10, v11; float w00, w01, w10, w11; };
    struct AF2 { short8v c0i0, c0i1, c0i2, c0i3, c1i0, c1i1, c1i2, c1i3; };

    auto loadA = [&](int kt) -> AF2 {           // panel -> regs (L2-resident)
        const unsigned short* pnl = W2p + ((size_t)kt * 2048) * 8;
        const int b0 = quad * 256 + wm * 64 + r15;
        const int b1 = (4 + quad) * 256 + wm * 64 + r15;
        AF2 r;
        r.c0i0 = *(const short8v*)(pnl + (size_t)(b0 +  0) * 8);
        r.c0i1 = *(const short8v*)(pnl + (size_t)(b0 + 16) * 8);
        r.c0i2 = *(const short8v*)(pnl + (size_t)(b0 + 32) * 8);
        r.c0i3 = *(const short8v*)(pnl + (size_t)(b0 + 48) * 8);
        r.c1i0 = *(const short8v*)(pnl + (size_t)(b1 +  0) * 8);
        r.c1i1 = *(const short8v*)(pnl + (size_t)(b1 + 16) * 8);
        r.c1i2 = *(const short8v*)(pnl + (size_t)(b1 + 32) * 8);
        r.c1i3 = *(const short8v*)(pnl + (size_t)(b1 + 48) * 8);
        return r;
    };
    // issue phase: address math + 4 gathers into regs (R9-verbatim per-pixel math)
    auto sampIssue = [&](int kt) -> Samp {
        Samp s;
        const int kk = kt >> 2, g = kt & 3;
        const int o_dy = (g * 9 + kk) * 2, o_dx = o_dy + 1;
        const float dy = fmaf(offset_w[o_dy * 2], s01.x, offset_w[o_dy * 2 + 1] * s01.y);
        const float dx = fmaf(offset_w[o_dx * 2], s01.x, offset_w[o_dx * 2 + 1] * s01.y);
        const float py = (float)(y + kk / 3 - 1) + dy;
        const float px = (float)(x + kk % 3 - 1) + dx;
        const float y0f = floorf(py), x0f = floorf(px);
        const float wy = py - y0f, wx = px - x0f;
        const int y0 = (int)y0f, x0 = (int)x0f;
        const int y1 = y0 + 1, x1 = x0 + 1;
        const bool vy0 = (y0 >= 0) && (y0 < HH), vy1 = (y1 >= 0) && (y1 < HH);
        const bool vx0 = (x0 >= 0) && (x0 < WW), vx1 = (x1 >= 0) && (x1 < WW);
        const int y0c = min(max(y0, 0), HH - 1), y1c = min(max(y1, 0), HH - 1);
        const int x0c = min(max(x0, 0), WW - 1), x1c = min(max(x1, 0), WW - 1);
        s.w00 = (vy0 && vx0) ? (1.f - wy) * (1.f - wx) : 0.f;
        s.w01 = (vy0 && vx1) ? (1.f - wy) * wx         : 0.f;
        s.w10 = (vy1 && vx0) ? wy * (1.f - wx)         : 0.f;
        s.w11 = (vy1 && vx1) ? wy * wx                 : 0.f;
        const int ch = g * 64 + kc * 8;
        s.v00 = *(const short8v*)(tb + (size_t)(y0c * WW + x0c) * CC + ch);
        s.v01 = *(const short8v*)(tb + (size_t)(y0c * WW + x1c) * CC + ch);
        s.v10 = *(const short8v*)(tb + (size_t)(y1c * WW + x0c) * CC + ch);
        s.v11 = *(const short8v*)(tb + (size_t)(y1c * WW + x1c) * CC + ch);
        return s;
    };
    // finish phase: bilinear blend + bf16 round + swizzled ds_write
    auto sampFinish = [&](const Samp& s, int buf) {
        short8v r;
#pragma unroll
        for (int e = 0; e < 8; e++) {
            float val = s.w00 * bf2f((unsigned short)s.v00[e]);
            val = fmaf(s.w01, bf2f((unsigned short)s.v01[e]), val);
            val = fmaf(s.w10, bf2f((unsigned short)s.v10[e]), val);
            val = fmaf(s.w11, bf2f((unsigned short)s.v11[e]), val);
            r[e] = (short)f2bf(val);
        }
        *(short8v*)&Bs[buf][xsw] = r;
    };
    auto mma = [&](int buf, const AF2& a) {
        {   // ks = 0, kchunk = quad
            const int kchunk = quad;
            const int row0 = r15, row1 = 16 + r15;
            short8v bf0 = *(const short8v*)&Bs[buf][(row0 * 8 + (kchunk ^ (row0 & 7))) * 8];
            short8v bf1 = *(const short8v*)&Bs[buf][(row1 * 8 + (kchunk ^ (row1 & 7))) * 8];
            acc[0][0] = __builtin_amdgcn_mfma_f32_16x16x32_bf16(a.c0i0, bf0, acc[0][0], 0, 0, 0);
            acc[0][1] = __builtin_amdgcn_mfma_f32_16x16x32_bf16(a.c0i0, bf1, acc[0][1], 0, 0, 0);
            acc[1][0] = __builtin_amdgcn_mfma_f32_16x16x32_bf16(a.c0i1, bf0, acc[1][0], 0, 0, 0);
            acc[1][1] = __builtin_amdgcn_mfma_f32_16x16x32_bf16(a.c0i1, bf1, acc[1][1], 0, 0, 0);
            acc[2][0] = __builtin_amdgcn_mfma_f32_16x16x32_bf16(a.c0i2, bf0, acc[2][0], 0, 0, 0);
            acc[2][1] = __builtin_amdgcn_mfma_f32_16x16x32_bf16(a.c0i2, bf1, acc[2][1], 0, 0, 0);
            acc[3][0] = __builtin_amdgcn_mfma_f32_16x16x32_bf16(a.c0i3, bf0, acc[3][0], 0, 0, 0);
            acc[3][1] = __builtin_amdgcn_mfma_f32_16x16x32_bf16(a.c0i3, bf1, acc[3][1], 0, 0, 0);
        }
        {   // ks = 1, kchunk = 4 + quad
            const int kchunk = 4 + quad;
            const int row0 = r15, row1 = 16 + r15;
            short8v bf0 = *(const short8v*)&Bs[buf][(row0 * 8 + (kchunk ^ (row0 & 7))) * 8];
            short8v bf1 = *(const short8v*)&Bs[buf][(row1 * 8 + (kchunk ^ (row1 & 7))) * 8];
            acc[0][0] = __builtin_amdgcn_mfma_f32_16x16x32_bf16(a.c1i0, bf0, acc[0][0], 0, 0, 0);
            acc[0][1] = __builtin_amdgcn_mfma_f32_16x16x32_bf16(a.c1i0, bf1, acc[0][1], 0, 0, 0);
            acc[1][0] = __builtin_amdgcn_mfma_f32_16x16x32_bf16(a.c1i1, bf0, acc[1][0], 0, 0, 0);
            acc[1][1] = __builtin_amdgcn_mfma_f32_16x16x32_bf16(a.c1i1, bf1, acc[1][1], 0, 0, 0);
            acc[2][0] = __builtin_amdgcn_mfma_f32_16x16x32_bf16(a.c1i2, bf0, acc[2][0], 0, 0, 0);
            acc[2][1] = __builtin_amdgcn_mfma_f32_16x16x32_bf16(a.c1i2, bf1, acc[2][1], 0, 0, 0);
            acc[3][0] = __builtin_amdgcn_mfma_f32_16x16x32_bf16(a.c1i3, bf0, acc[3][0], 0, 0, 0);
            acc[3][1] = __builtin_amdgcn_mfma_f32_16x16x32_bf16(a.c1i3, bf1, acc[3][1], 0, 0, 0);
        }
    };

    // ---- K-loop over all 36 kts (full-K), 2x-unrolled, named afA/afB ----
    AF2 afA = loadA(0), afB;
    { Samp s = sampIssue(0); sampFinish(s, 0); }
    __syncthreads();
    int cur = 0;
    for (int k2 = 0; k2 < (NKT - 2) / 2; k2++) {
        const int kt = 2 * k2;
        {   // step kt: consume afA, prefetch afB = A(kt+1)
            const int nxt = cur ^ 1;
            afB = loadA(kt + 1);
            Samp s = sampIssue(kt + 1);
            mma(cur, afA);
            sampFinish(s, nxt);
            __syncthreads();
            cur = nxt;
        }
        {   // step kt+1: consume afB, prefetch afA = A(kt+2)
            const int nxt = cur ^ 1;
            afA = loadA(kt + 2);
            Samp s = sampIssue(kt + 2);
            mma(cur, afB);
            sampFinish(s, nxt);
            __syncthreads();
            cur = nxt;
        }
    }
    {   // step NKT-2 = 34: consume afA, prefetch afB = A(35)
        const int nxt = cur ^ 1;
        afB = loadA(NKT - 1);
        Samp s = sampIssue(NKT - 1);
        mma(cur, afA);
        sampFinish(s, nxt);
        __syncthreads();
        cur = nxt;
    }
    mma(cur, afB);                              // step 35

    // ---- fused epilogue: relu + cls/bbox dots, cross-wave reduce ----
    float pc[2]  = {0.f, 0.f};
    float pb0[2] = {0.f, 0.f}, pb1[2] = {0.f, 0.f};
    float pb2[2] = {0.f, 0.f}, pb3[2] = {0.f, 0.f};
#pragma unroll
    for (int i = 0; i < 4; i++) {
        const int m = wm * 64 + i * 16 + quad * 4;
        const float4 cw  = *(const float4*)(cls_w + m);
        const float4 b0w = *(const float4*)(bbox_w + m);
        const float4 b1w = *(const float4*)(bbox_w + CC + m);
        const float4 b2w = *(const float4*)(bbox_w + 2 * CC + m);
        const float4 b3w = *(const float4*)(bbox_w + 3 * CC + m);
#pragma unroll
        for (int j = 0; j < 2; j++) {
            const float t0 = fmaxf(acc[i][j][0], 0.f);
            const float t1 = fmaxf(acc[i][j][1], 0.f);
            const float t2 = fmaxf(acc[i][j][2], 0.f);
            const float t3 = fmaxf(acc[i][j][3], 0.f);
            pc[j]  = fmaf(cw.x,  t0, fmaf(cw.y,  t1, fmaf(cw.z,  t2, fmaf(cw.w,  t3, pc[j]))));
            pb0[j] = fmaf(b0w.x, t0, fmaf(b0w.y, t1, fmaf(b0w.z, t2, fmaf(b0w.w, t3, pb0[j]))));
            pb1[j] = fmaf(b1w.x, t0, fmaf(b1w.y, t1, fmaf(b1w.z, t2, fmaf(b1w.w, t3, pb1[j]))));
            pb2[j] = fmaf(b2w.x, t0, fmaf(b2w.y, t1, fmaf(b2w.z, t2, fmaf(b2w.w, t3, pb2[j]))));
            pb3[j] = fmaf(b3w.x, t0, fmaf(b3w.y, t1, fmaf(b3w.z, t2, fmaf(b3w.w, t3, pb3[j]))));
        }
    }
    // reduce across quad (lanes r15 + 16*quad): xor 16, 32 sums all 4 quads
#pragma unroll
    for (int j = 0; j < 2; j++) {
#pragma unroll
        for (int off = 16; off <= 32; off <<= 1) {
            pc[j]  += __shfl_xor(pc[j],  off);
            pb0[j] += __shfl_xor(pb0[j], off);
            pb1[j] += __shfl_xor(pb1[j], off);
            pb2[j] += __shfl_xor(pb2[j], off);
            pb3[j] += __shfl_xor(pb3[j], off);
        }
    }
    if (quad == 0) {                            // lanes 0..15 hold reduced vals
#pragma unroll
        for (int j = 0; j < 2; j++) {
            const int nl = j * 16 + r15;
            sm[wm][nl][0] = pc[j];
            sm[wm][nl][1] = pb0[j];
            sm[wm][nl][2] = pb1[j];
            sm[wm][nl][3] = pb2[j];
            sm[wm][nl][4] = pb3[j];
        }
    }
    __syncthreads();
    if (tid < 32) {                             // one thread per pixel
        const int n = n0 + tid;
        const int bb = n / HWP, pp = n - bb * HWP;
        const float vc = sm[0][tid][0] + sm[1][tid][0] + sm[2][tid][0] + sm[3][tid][0];
        const float v0 = sm[0][tid][1] + sm[1][tid][1] + sm[2][tid][1] + sm[3][tid][1];
        const float v1 = sm[0][tid][2] + sm[1][tid][2] + sm[2][tid][2] + sm[3][tid][2];
        const float v2 = sm[0][tid][3] + sm[1][tid][3] + sm[2][tid][3] + sm[3][tid][3];
        const float v3 = sm[0][tid][4] + sm[1][tid][4] + sm[2][tid][4] + sm[3][tid][4];
        out[OUT_LOGITS + n] = vc + cls_b[0];
        out[OUT_BBOX + (bb * 4 + 0) * HWP + pp] = v0 + bbox_b[0];
        out[OUT_BBOX + (bb * 4 + 1) * HWP + pp] = v1 + bbox_b[1];
        out[OUT_BBOX + (bb * 4 + 2) * HWP + pp] = v2 + bbox_b[2];
        out[OUT_BBOX + (bb * 4 + 3) * HWP + pp] = v3 + bbox_b[3];
    }
}

// ----------------------------------------------------------------------------
extern "C" void kernel_launch(void* const* d_in, const int* in_sizes, int n_in,
                              void* d_out, int out_size, void* d_ws, size_t ws_size,
                              hipStream_t stream)
{
    const float* feature  = (const float*)d_in[0];
    const float* conv_w   = (const float*)d_in[1];
    const float* conv_b   = (const float*)d_in[2];
    const float* loc_w    = (const float*)d_in[3];
    const float* loc_b    = (const float*)d_in[4];
    const float* shape_w  = (const float*)d_in[5];
    const float* shape_b  = (const float*)d_in[6];
    const float* offset_w = (const float*)d_in[7];
    const float* adapt_w  = (const float*)d_in[8];
    const float* cls_w    = (const float*)d_in[9];
    const float* cls_b    = (const float*)d_in[10];
    const float* bbox_w   = (const float*)d_in[11];
    const float* bbox_b   = (const float*)d_in[12];
    float* out = (float*)d_out;

    // workspace partition (~22 MB — pta eliminated)
    float*          s0s1 = (float*)d_ws;                           // NTOT float2
    unsigned short* tcf  = (unsigned short*)(s0s1 + 2 * NTOT);     // NTOT*CC bf16
    unsigned short* fcf  = tcf + (size_t)NTOT * CC;                // NTOT*CC bf16
    unsigned short* W1p  = fcf + (size_t)NTOT * CC;                // CC*K1 bf16 (panels)
    unsigned short* W2p  = W1p + (size_t)CC * K1;                  // CC*K1 bf16 (panels)
    unsigned short* zp   = W2p + (size_t)CC * K1;                  // 1024 zeros

    prep_kernel<<<(CC * K1 + 255) / 256, 256, 0, stream>>>(conv_w, adapt_w, W1p, W2p, zp);
    transpose_kernel<<<dim3(HWP / 64, 4, BB), 256, 0, stream>>>(feature, fcf);
    gemm1_kernel<<<dim3(NTOT / 64 * 2), 512, 0, stream>>>(W1p, fcf, conv_b, zp, tcf);
    heads1_kernel<<<dim3(NTOT / 4), 256, 0, stream>>>(
        tcf, loc_w, loc_b, shape_w, shape_b, out, s0s1);
    gemm2_fused_kernel<<<dim3(NTOT / 32), 256, 0, stream>>>(
        W2p, tcf, s0s1, offset_w, cls_w, cls_b, bbox_w, bbox_b, out);
}

// Round 19
// 193.873 us; speedup vs baseline: 1.0885x; 1.0126x over previous
//
#include <hip/hip_runtime.h>
#include <hip/hip_bf16.h>

// Problem constants
#define BB 2
#define CC 256
#define HH 96
#define WW 96
#define HWP (HH*WW)        // 9216
#define NTOT (BB*HWP)      // 18432 flattened (b,p)
#define K1 2304            // 256*9, GEMM K for both convs
#define NKT 36             // K1/64 k-steps

// d_out layout: logits[2,1,96,96], bbox[2,4,96,96], shape[2,2,96,96], loc[2,1,96,96]
#define OUT_LOGITS 0
#define OUT_BBOX   (2*1*HWP)
#define OUT_SHAPE  (OUT_BBOX + 2*4*HWP)
#define OUT_LOC    (OUT_SHAPE + 2*2*HWP)

typedef __attribute__((ext_vector_type(8))) short short8v;   // 8 bf16 (4 VGPRs)
typedef __attribute__((ext_vector_type(4))) float f32x4;

// XCD-aware swizzles: contiguous slab of consecutive n-blocks per XCD.
__device__ __forceinline__ int xcd_swizzle288(int bx) {    // 288 = 8 x 36
    return (bx & 7) * 36 + (bx >> 3);
}
__device__ __forceinline__ int xcd_swizzle576(int bx) {    // 576 = 8 x 72
    return (bx & 7) * 72 + (bx >> 3);
}

__device__ __forceinline__ float bf2f(unsigned short u) {
    return __uint_as_float(((unsigned)u) << 16);
}
__device__ __forceinline__ unsigned short f2bf(float f) {
    unsigned u = __float_as_uint(f);
    u += 0x7FFFu + ((u >> 16) & 1u);           // round-to-nearest-even
    return (unsigned short)(u >> 16);
}

// ------- prep: weights -> bf16 PRE-SWIZZLED A panels + zero page ------------
__global__ __launch_bounds__(256) void prep_kernel(
    const float* __restrict__ conv_w, const float* __restrict__ adapt_w,
    unsigned short* __restrict__ W1p, unsigned short* __restrict__ W2p,
    unsigned short* __restrict__ zp)
{
    const int t = blockIdx.x * 256 + threadIdx.x;
    if (t < 1024) zp[t] = 0;                    // zero page (ws is re-poisoned!)
    if (t < CC * K1) {
        const int e = t & 7;
        {   // W1p
            const int s  = (t >> 3) & 1023;
            const int r  = t >> 13;             // cb*36+kt, [0,72)
            const int kt = r % 36, cb = r / 36;
            const int row = s & 127, kc = s >> 7;
            const int co = cb * 128 + row;
            const int k  = kt * 64 + kc * 8 + e;
            const int kk = k >> 8, ci = k & 255;
            W1p[t] = f2bf(conv_w[co * K1 + ci * 9 + kk]);
        }
        {   // W2p
            const int s  = (t >> 3) & 2047;
            const int kt = t >> 14;             // [0,36)
            const int row = s & 255, kc = s >> 8;
            const int k  = kt * 64 + kc * 8 + e;
            const int kk = k >> 8, ci = k & 255;
            W2p[t] = f2bf(adapt_w[row * K1 + ci * 9 + kk]);
        }
    }
}

// ------------- transpose feature [b][c][p] fp32 -> f_cf [b][p][c] bf16 ------
// R12: store phase vectorized to ushort4 (512 B/wave-instr vs 128 B scalar).
__global__ __launch_bounds__(256) void transpose_kernel(
    const float* __restrict__ f, unsigned short* __restrict__ fcf)
{
    __shared__ unsigned short tile[64][66];     // +2 pad
    const int p0 = blockIdx.x * 64;
    const int cc = blockIdx.y;
    const int b  = blockIdx.z;
    const int tx = threadIdx.x & 63, ty = threadIdx.x >> 6;
#pragma unroll
    for (int ii = 0; ii < 16; ii++) {
        const int cl = ii * 4 + ty;
        tile[cl][tx] = f2bf(f[((size_t)b * CC + cc * 64 + cl) * HWP + p0 + tx]);
    }
    __syncthreads();
    const int tx4 = threadIdx.x & 15;           // c-quad index (c = tx4*4..+3)
    const int py  = threadIdx.x >> 4;           // pixel sub-index (0..15)
#pragma unroll
    for (int ii = 0; ii < 4; ii++) {
        const int pl = ii * 16 + py;
        ushort4 v;
        v.x = tile[tx4 * 4 + 0][pl];
        v.y = tile[tx4 * 4 + 1][pl];
        v.z = tile[tx4 * 4 + 2][pl];
        v.w = tile[tx4 * 4 + 3][pl];
        *(ushort4*)(fcf + ((size_t)(b * HWP + p0 + pl)) * CC + cc * 64 + tx4 * 4) = v;
    }
}

// --------- GEMM1 + fused heads1 partials, 512 thr / 8 waves -----------------
// M=128 x N=64, BK=64. K-loop R13-exact (cb in bx&1, A-direct from L2,
// depth-1 B prefetch). R19: epilogue additionally computes the loc/shape
// partial dots over this block's 128 channels in fp32 (R14 fusion pattern:
// per-thread dots -> quad shuffle -> LDS cross-wave reduce) and writes
// part[n][cb][3] (442 KB). combine_kernel sums the cb halves (replaces the
// 9.4 MB tcf re-read of heads1).
__global__ __launch_bounds__(512, 6) void gemm1_kernel(
    const unsigned short* __restrict__ W1p, const unsigned short* __restrict__ fcf,
    const float* __restrict__ bias, const unsigned short* __restrict__ zp,
    const float* __restrict__ loc_w, const float* __restrict__ shape_w,
    unsigned short* __restrict__ tcf, float* __restrict__ part)
{
    __shared__ short Bs[2][4096];               // 2 x 8 KB (XOR-swizzled)
    __shared__ float sm1[4][64][4];             // [wm][pixel][3 dots + pad] 4 KB
    const int tid  = threadIdx.x;
    const int lane = tid & 63, w = tid >> 6;    // w in [0,8)
    const int quad = lane >> 4, r15 = lane & 15;
    const int cb  = blockIdx.x & 1;             // interleaved co-half
    const int n0  = xcd_swizzle288(blockIdx.x >> 1) * 64;
    const int co0 = cb * 128;
    const int wm = w & 3, wn = w >> 2;          // co-quarter (32 rows), n-half

    // B staging geometry: thread -> (pixel pr, 8-ch chunk kc)
    const int pr = tid >> 3, kc = tid & 7;
    const int xsw = (pr * 8 + (kc ^ (pr & 7))) * 8;   // Bs write slot (shorts)
    const int nb = n0 + pr;
    const int b  = nb / HWP;
    const int p  = nb - b * HWP;
    const int y = p / WW, x = p % WW;
    const unsigned short* fb = fcf + (size_t)b * HWP * CC;

    f32x4 acc[2][2];
#pragma unroll
    for (int i = 0; i < 2; i++)
#pragma unroll
        for (int j = 0; j < 2; j++) acc[i][j] = (f32x4){0.f, 0.f, 0.f, 0.f};

    auto loadB = [&](int kt) -> short8v {
        const int kk  = kt >> 2;
        const int ci0 = (kt & 3) * 64;
        const int yy = y + kk / 3 - 1, xx = x + kk % 3 - 1;
        const bool ok = (yy >= 0) && (yy < HH) && (xx >= 0) && (xx < WW);
        const unsigned short* src = ok
            ? fb + (size_t)(yy * WW + xx) * CC + ci0 + kc * 8
            : zp;
        return *(const short8v*)src;
    };
    // A-fragment direct from global: slot = kchunk*128 + row within kt-panel.
    auto mma = [&](int buf, int kt) {
        const unsigned short* pnl = W1p + ((size_t)(cb * 36 + kt) * 1024) * 8;
#pragma unroll
        for (int ks = 0; ks < 2; ks++) {
            short8v a[2], bf[2];
            const int kchunk = ks * 4 + quad;
#pragma unroll
            for (int i = 0; i < 2; i++)
                a[i] = *(const short8v*)(pnl + (size_t)(kchunk * 128 + wm * 32 + i * 16 + r15) * 8);
#pragma unroll
            for (int j = 0; j < 2; j++) {
                const int row = wn * 32 + j * 16 + r15;
                bf[j] = *(const short8v*)&Bs[buf][(row * 8 + (kchunk ^ (row & 7))) * 8];
            }
#pragma unroll
            for (int i = 0; i < 2; i++)
#pragma unroll
                for (int j = 0; j < 2; j++)
                    acc[i][j] = __builtin_amdgcn_mfma_f32_16x16x32_bf16(a[i], bf[j], acc[i][j], 0, 0, 0);
        }
    };

    { short8v b0 = loadB(0); *(short8v*)&Bs[0][xsw] = b0; }
    __syncthreads();
    int cur = 0;
    for (int kt = 0; kt < NKT - 1; kt++) {
        const int nxt = cur ^ 1;
        short8v bn = loadB(kt + 1);             // -> regs, latency under MFMA
        mma(cur, kt);
        *(short8v*)&Bs[nxt][xsw] = bn;
        __syncthreads();
        cur = nxt;
    }
    mma(cur, NKT - 1);                          // peeled last tile

    // epilogue: bias + relu (fp32) -> tcf bf16, + loc/shape partial dots
    float pl[2] = {0.f, 0.f}, p0s[2] = {0.f, 0.f}, p1s[2] = {0.f, 0.f};
#pragma unroll
    for (int i = 0; i < 2; i++) {
        const int m = co0 + wm * 32 + i * 16 + quad * 4;
        const float b0 = bias[m], b1 = bias[m + 1], b2 = bias[m + 2], b3 = bias[m + 3];
        const float4 lw  = *(const float4*)(loc_w + m);
        const float4 s0w = *(const float4*)(shape_w + m);
        const float4 s1w = *(const float4*)(shape_w + CC + m);
#pragma unroll
        for (int j = 0; j < 2; j++) {
            const int n = n0 + wn * 32 + j * 16 + r15;
            const float t0 = fmaxf(acc[i][j][0] + b0, 0.f);
            const float t1 = fmaxf(acc[i][j][1] + b1, 0.f);
            const float t2 = fmaxf(acc[i][j][2] + b2, 0.f);
            const float t3 = fmaxf(acc[i][j][3] + b3, 0.f);
            ushort4 st;
            st.x = f2bf(t0); st.y = f2bf(t1); st.z = f2bf(t2); st.w = f2bf(t3);
            *(ushort4*)(tcf + (size_t)n * CC + m) = st;
            pl[j]  = fmaf(lw.x,  t0, fmaf(lw.y,  t1, fmaf(lw.z,  t2, fmaf(lw.w,  t3, pl[j]))));
            p0s[j] = fmaf(s0w.x, t0, fmaf(s0w.y, t1, fmaf(s0w.z, t2, fmaf(s0w.w, t3, p0s[j]))));
            p1s[j] = fmaf(s1w.x, t0, fmaf(s1w.y, t1, fmaf(s1w.z, t2, fmaf(s1w.w, t3, p1s[j]))));
        }
    }
    // reduce across quads (lanes share r15): xor 16, 32 sums all 4 quads
#pragma unroll
    for (int j = 0; j < 2; j++) {
#pragma unroll
        for (int off = 16; off <= 32; off <<= 1) {
            pl[j]  += __shfl_xor(pl[j],  off);
            p0s[j] += __shfl_xor(p0s[j], off);
            p1s[j] += __shfl_xor(p1s[j], off);
        }
    }
    if (quad == 0) {                            // lanes 0..15 hold reduced vals
#pragma unroll
        for (int j = 0; j < 2; j++) {
            const int pix = wn * 32 + j * 16 + r15;
            sm1[wm][pix][0] = pl[j];
            sm1[wm][pix][1] = p0s[j];
            sm1[wm][pix][2] = p1s[j];
        }
    }
    __syncthreads();
    if (tid < 64) {                             // one thread per pixel
        const int n = n0 + tid;
        const float a0 = sm1[0][tid][0] + sm1[1][tid][0] + sm1[2][tid][0] + sm1[3][tid][0];
        const float a1 = sm1[0][tid][1] + sm1[1][tid][1] + sm1[2][tid][1] + sm1[3][tid][1];
        const float a2 = sm1[0][tid][2] + sm1[1][tid][2] + sm1[2][tid][2] + sm1[3][tid][2];
        float* dst = part + (size_t)n * 6 + cb * 3;
        dst[0] = a0; dst[1] = a1; dst[2] = a2;
    }
}

// ---- combine: sum cb-halves of heads1 partials, add biases, emit outputs ---
__global__ __launch_bounds__(256) void combine_kernel(
    const float* __restrict__ part,
    const float* __restrict__ loc_b, const float* __restrict__ shape_b,
    float* __restrict__ out, float* __restrict__ s0s1)
{
    const int n = blockIdx.x * 256 + threadIdx.x;
    const int b = n / HWP, p = n - b * HWP;
    const float* pr = part + (size_t)n * 6;
    const float al = pr[0] + pr[3] + loc_b[0];
    const float a  = pr[1] + pr[4] + shape_b[0];
    const float c2 = pr[2] + pr[5] + shape_b[1];
    out[OUT_LOC + n] = al;
    out[OUT_SHAPE + (b * 2 + 0) * HWP + p] = a;
    out[OUT_SHAPE + (b * 2 + 1) * HWP + p] = c2;
    *(float2*)&s0s1[2 * n] = make_float2(a, c2);
}

// ---- fused GEMM2 + heads2, FULL-K, M=256 x N=32, 256 thr / 4 waves ---------
// R14-exact (best round): full-K, A-reg-prefetch (named-member struct),
// depth-1 sampler, one __syncthreads per kt, fused cls/bbox epilogue.
__global__ __launch_bounds__(256, 3) void gemm2_fused_kernel(
    const unsigned short* __restrict__ W2p, const unsigned short* __restrict__ tcf,
    const float* __restrict__ s0s1, const float* __restrict__ offset_w,
    const float* __restrict__ cls_w, const float* __restrict__ cls_b,
    const float* __restrict__ bbox_w, const float* __restrict__ bbox_b,
    float* __restrict__ out)
{
    __shared__ short Bs[2][2048];               // 2 x 4 KB (32 rows x 8 chunks, XOR)
    __shared__ float sm[4][32][6];              // [wave][n][5 heads], +1 pad
    const int tid  = threadIdx.x;
    const int lane = tid & 63, wm = tid >> 6;   // 4 waves, wm = co-quarter (64 rows)
    const int quad = lane >> 4, r15 = lane & 15;
    const int n0  = xcd_swizzle576(blockIdx.x) * 32;
    const int b   = n0 / HWP;                   // whole block in one batch
    const unsigned short* tb = tcf + (size_t)b * HWP * CC;

    // sampler mapping: thread -> pixel pr (0..31), 8-ch chunk kc (one px/thread)
    const int pr = tid >> 3, kc = tid & 7;
    const int xsw = (pr * 8 + (kc ^ (pr & 7))) * 8;   // Bs write slot (shorts)
    const int nb = n0 + pr;
    const int p  = nb - b * HWP;
    const int y = p / WW, x = p % WW;
    const float2 s01 = *(const float2*)&s0s1[2 * nb];

    f32x4 acc[4][2];
#pragma unroll
    for (int i = 0; i < 4; i++)
#pragma unroll
        for (int j = 0; j < 2; j++) acc[i][j] = (f32x4){0.f, 0.f, 0.f, 0.f};

    struct Samp { short8v v00, v01, v10, v11; float w00, w01, w10, w11; };
    struct AF2 { short8v c0i0, c0i1, c0i2, c0i3, c1i0, c1i1, c1i2, c1i3; };

    auto loadA = [&](int kt) -> AF2 {           // panel -> regs (L2-resident)
        const unsigned short* pnl = W2p + ((size_t)kt * 2048) * 8;
        const int b0 = quad * 256 + wm * 64 + r15;
        const int b1 = (4 + quad) * 256 + wm * 64 + r15;
        AF2 r;
        r.c0i0 = *(const short8v*)(pnl + (size_t)(b0 +  0) * 8);
        r.c0i1 = *(const short8v*)(pnl + (size_t)(b0 + 16) * 8);
        r.c0i2 = *(const short8v*)(pnl + (size_t)(b0 + 32) * 8);
        r.c0i3 = *(const short8v*)(pnl + (size_t)(b0 + 48) * 8);
        r.c1i0 = *(const short8v*)(pnl + (size_t)(b1 +  0) * 8);
        r.c1i1 = *(const short8v*)(pnl + (size_t)(b1 + 16) * 8);
        r.c1i2 = *(const short8v*)(pnl + (size_t)(b1 + 32) * 8);
        r.c1i3 = *(const short8v*)(pnl + (size_t)(b1 + 48) * 8);
        return r;
    };
    // issue phase: address math + 4 gathers into regs (R9-verbatim per-pixel math)
    auto sampIssue = [&](int kt) -> Samp {
        Samp s;
        const int kk = kt >> 2, g = kt & 3;
        const int o_dy = (g * 9 + kk) * 2, o_dx = o_dy + 1;
        const float dy = fmaf(offset_w[o_dy * 2], s01.x, offset_w[o_dy * 2 + 1] * s01.y);
        const float dx = fmaf(offset_w[o_dx * 2], s01.x, offset_w[o_dx * 2 + 1] * s01.y);
        const float py = (float)(y + kk / 3 - 1) + dy;
        const float px = (float)(x + kk % 3 - 1) + dx;
        const float y0f = floorf(py), x0f = floorf(px);
        const float wy = py - y0f, wx = px - x0f;
        const int y0 = (int)y0f, x0 = (int)x0f;
        const int y1 = y0 + 1, x1 = x0 + 1;
        const bool vy0 = (y0 >= 0) && (y0 < HH), vy1 = (y1 >= 0) && (y1 < HH);
        const bool vx0 = (x0 >= 0) && (x0 < WW), vx1 = (x1 >= 0) && (x1 < WW);
        const int y0c = min(max(y0, 0), HH - 1), y1c = min(max(y1, 0), HH - 1);
        const int x0c = min(max(x0, 0), WW - 1), x1c = min(max(x1, 0), WW - 1);
        s.w00 = (vy0 && vx0) ? (1.f - wy) * (1.f - wx) : 0.f;
        s.w01 = (vy0 && vx1) ? (1.f - wy) * wx         : 0.f;
        s.w10 = (vy1 && vx0) ? wy * (1.f - wx)         : 0.f;
        s.w11 = (vy1 && vx1) ? wy * wx                 : 0.f;
        const int ch = g * 64 + kc * 8;
        s.v00 = *(const short8v*)(tb + (size_t)(y0c * WW + x0c) * CC + ch);
        s.v01 = *(const short8v*)(tb + (size_t)(y0c * WW + x1c) * CC + ch);
        s.v10 = *(const short8v*)(tb + (size_t)(y1c * WW + x0c) * CC + ch);
        s.v11 = *(const short8v*)(tb + (size_t)(y1c * WW + x1c) * CC + ch);
        return s;
    };
    // finish phase: bilinear blend + bf16 round + swizzled ds_write
    auto sampFinish = [&](const Samp& s, int buf) {
        short8v r;
#pragma unroll
        for (int e = 0; e < 8; e++) {
            float val = s.w00 * bf2f((unsigned short)s.v00[e]);
            val = fmaf(s.w01, bf2f((unsigned short)s.v01[e]), val);
            val = fmaf(s.w10, bf2f((unsigned short)s.v10[e]), val);
            val = fmaf(s.w11, bf2f((unsigned short)s.v11[e]), val);
            r[e] = (short)f2bf(val);
        }
        *(short8v*)&Bs[buf][xsw] = r;
    };
    auto mma = [&](int buf, const AF2& a) {
        {   // ks = 0, kchunk = quad
            const int kchunk = quad;
            const int row0 = r15, row1 = 16 + r15;
            short8v bf0 = *(const short8v*)&Bs[buf][(row0 * 8 + (kchunk ^ (row0 & 7))) * 8];
            short8v bf1 = *(const short8v*)&Bs[buf][(row1 * 8 + (kchunk ^ (row1 & 7))) * 8];
            acc[0][0] = __builtin_amdgcn_mfma_f32_16x16x32_bf16(a.c0i0, bf0, acc[0][0], 0, 0, 0);
            acc[0][1] = __builtin_amdgcn_mfma_f32_16x16x32_bf16(a.c0i0, bf1, acc[0][1], 0, 0, 0);
            acc[1][0] = __builtin_amdgcn_mfma_f32_16x16x32_bf16(a.c0i1, bf0, acc[1][0], 0, 0, 0);
            acc[1][1] = __builtin_amdgcn_mfma_f32_16x16x32_bf16(a.c0i1, bf1, acc[1][1], 0, 0, 0);
            acc[2][0] = __builtin_amdgcn_mfma_f32_16x16x32_bf16(a.c0i2, bf0, acc[2][0], 0, 0, 0);
            acc[2][1] = __builtin_amdgcn_mfma_f32_16x16x32_bf16(a.c0i2, bf1, acc[2][1], 0, 0, 0);
            acc[3][0] = __builtin_amdgcn_mfma_f32_16x16x32_bf16(a.c0i3, bf0, acc[3][0], 0, 0, 0);
            acc[3][1] = __builtin_amdgcn_mfma_f32_16x16x32_bf16(a.c0i3, bf1, acc[3][1], 0, 0, 0);
        }
        {   // ks = 1, kchunk = 4 + quad
            const int kchunk = 4 + quad;
            const int row0 = r15, row1 = 16 + r15;
            short8v bf0 = *(const short8v*)&Bs[buf][(row0 * 8 + (kchunk ^ (row0 & 7))) * 8];
            short8v bf1 = *(const short8v*)&Bs[buf][(row1 * 8 + (kchunk ^ (row1 & 7))) * 8];
            acc[0][0] = __builtin_amdgcn_mfma_f32_16x16x32_bf16(a.c1i0, bf0, acc[0][0], 0, 0, 0);
            acc[0][1] = __builtin_amdgcn_mfma_f32_16x16x32_bf16(a.c1i0, bf1, acc[0][1], 0, 0, 0);
            acc[1][0] = __builtin_amdgcn_mfma_f32_16x16x32_bf16(a.c1i1, bf0, acc[1][0], 0, 0, 0);
            acc[1][1] = __builtin_amdgcn_mfma_f32_16x16x32_bf16(a.c1i1, bf1, acc[1][1], 0, 0, 0);
            acc[2][0] = __builtin_amdgcn_mfma_f32_16x16x32_bf16(a.c1i2, bf0, acc[2][0], 0, 0, 0);
            acc[2][1] = __builtin_amdgcn_mfma_f32_16x16x32_bf16(a.c1i2, bf1, acc[2][1], 0, 0, 0);
            acc[3][0] = __builtin_amdgcn_mfma_f32_16x16x32_bf16(a.c1i3, bf0, acc[3][0], 0, 0, 0);
            acc[3][1] = __builtin_amdgcn_mfma_f32_16x16x32_bf16(a.c1i3, bf1, acc[3][1], 0, 0, 0);
        }
    };

    // ---- K-loop over all 36 kts (full-K), 2x-unrolled, named afA/afB ----
    AF2 afA = loadA(0), afB;
    { Samp s = sampIssue(0); sampFinish(s, 0); }
    __syncthreads();
    int cur = 0;
    for (int k2 = 0; k2 < (NKT - 2) / 2; k2++) {
        const int kt = 2 * k2;
        {   // step kt: consume afA, prefetch afB = A(kt+1)
            const int nxt = cur ^ 1;
            afB = loadA(kt + 1);
            Samp s = sampIssue(kt + 1);
            mma(cur, afA);
            sampFinish(s, nxt);
            __syncthreads();
            cur = nxt;
        }
        {   // step kt+1: consume afB, prefetch afA = A(kt+2)
            const int nxt = cur ^ 1;
            afA = loadA(kt + 2);
            Samp s = sampIssue(kt + 2);
            mma(cur, afB);
            sampFinish(s, nxt);
            __syncthreads();
            cur = nxt;
        }
    }
    {   // step NKT-2 = 34: consume afA, prefetch afB = A(35)
        const int nxt = cur ^ 1;
        afB = loadA(NKT - 1);
        Samp s = sampIssue(NKT - 1);
        mma(cur, afA);
        sampFinish(s, nxt);
        __syncthreads();
        cur = nxt;
    }
    mma(cur, afB);                              // step 35

    // ---- fused epilogue: relu + cls/bbox dots, cross-wave reduce ----
    float pc[2]  = {0.f, 0.f};
    float pb0[2] = {0.f, 0.f}, pb1[2] = {0.f, 0.f};
    float pb2[2] = {0.f, 0.f}, pb3[2] = {0.f, 0.f};
#pragma unroll
    for (int i = 0; i < 4; i++) {
        const int m = wm * 64 + i * 16 + quad * 4;
        const float4 cw  = *(const float4*)(cls_w + m);
        const float4 b0w = *(const float4*)(bbox_w + m);
        const float4 b1w = *(const float4*)(bbox_w + CC + m);
        const float4 b2w = *(const float4*)(bbox_w + 2 * CC + m);
        const float4 b3w = *(const float4*)(bbox_w + 3 * CC + m);
#pragma unroll
        for (int j = 0; j < 2; j++) {
            const float t0 = fmaxf(acc[i][j][0], 0.f);
            const float t1 = fmaxf(acc[i][j][1], 0.f);
            const float t2 = fmaxf(acc[i][j][2], 0.f);
            const float t3 = fmaxf(acc[i][j][3], 0.f);
            pc[j]  = fmaf(cw.x,  t0, fmaf(cw.y,  t1, fmaf(cw.z,  t2, fmaf(cw.w,  t3, pc[j]))));
            pb0[j] = fmaf(b0w.x, t0, fmaf(b0w.y, t1, fmaf(b0w.z, t2, fmaf(b0w.w, t3, pb0[j]))));
            pb1[j] = fmaf(b1w.x, t0, fmaf(b1w.y, t1, fmaf(b1w.z, t2, fmaf(b1w.w, t3, pb1[j]))));
            pb2[j] = fmaf(b2w.x, t0, fmaf(b2w.y, t1, fmaf(b2w.z, t2, fmaf(b2w.w, t3, pb2[j]))));
            pb3[j] = fmaf(b3w.x, t0, fmaf(b3w.y, t1, fmaf(b3w.z, t2, fmaf(b3w.w, t3, pb3[j]))));
        }
    }
    // reduce across quad (lanes r15 + 16*quad): xor 16, 32 sums all 4 quads
#pragma unroll
    for (int j = 0; j < 2; j++) {
#pragma unroll
        for (int off = 16; off <= 32; off <<= 1) {
            pc[j]  += __shfl_xor(pc[j],  off);
            pb0[j] += __shfl_xor(pb0[j], off);
            pb1[j] += __shfl_xor(pb1[j], off);
            pb2[j] += __shfl_xor(pb2[j], off);
            pb3[j] += __shfl_xor(pb3[j], off);
        }
    }
    if (quad == 0) {                            // lanes 0..15 hold reduced vals
#pragma unroll
        for (int j = 0; j < 2; j++) {
            const int nl = j * 16 + r15;
            sm[wm][nl][0] = pc[j];
            sm[wm][nl][1] = pb0[j];
            sm[wm][nl][2] = pb1[j];
            sm[wm][nl][3] = pb2[j];
            sm[wm][nl][4] = pb3[j];
        }
    }
    __syncthreads();
    if (tid < 32) {                             // one thread per pixel
        const int n = n0 + tid;
        const int bb = n / HWP, pp = n - bb * HWP;
        const float vc = sm[0][tid][0] + sm[1][tid][0] + sm[2][tid][0] + sm[3][tid][0];
        const float v0 = sm[0][tid][1] + sm[1][tid][1] + sm[2][tid][1] + sm[3][tid][1];
        const float v1 = sm[0][tid][2] + sm[1][tid][2] + sm[2][tid][2] + sm[3][tid][2];
        const float v2 = sm[0][tid][3] + sm[1][tid][3] + sm[2][tid][3] + sm[3][tid][3];
        const float v3 = sm[0][tid][4] + sm[1][tid][4] + sm[2][tid][4] + sm[3][tid][4];
        out[OUT_LOGITS + n] = vc + cls_b[0];
        out[OUT_BBOX + (bb * 4 + 0) * HWP + pp] = v0 + bbox_b[0];
        out[OUT_BBOX + (bb * 4 + 1) * HWP + pp] = v1 + bbox_b[1];
        out[OUT_BBOX + (bb * 4 + 2) * HWP + pp] = v2 + bbox_b[2];
        out[OUT_BBOX + (bb * 4 + 3) * HWP + pp] = v3 + bbox_b[3];
    }
}

// ----------------------------------------------------------------------------
extern "C" void kernel_launch(void* const* d_in, const int* in_sizes, int n_in,
                              void* d_out, int out_size, void* d_ws, size_t ws_size,
                              hipStream_t stream)
{
    const float* feature  = (const float*)d_in[0];
    const float* conv_w   = (const float*)d_in[1];
    const float* conv_b   = (const float*)d_in[2];
    const float* loc_w    = (const float*)d_in[3];
    const float* loc_b    = (const float*)d_in[4];
    const float* shape_w  = (const float*)d_in[5];
    const float* shape_b  = (const float*)d_in[6];
    const float* offset_w = (const float*)d_in[7];
    const float* adapt_w  = (const float*)d_in[8];
    const float* cls_w    = (const float*)d_in[9];
    const float* cls_b    = (const float*)d_in[10];
    const float* bbox_w   = (const float*)d_in[11];
    const float* bbox_b   = (const float*)d_in[12];
    float* out = (float*)d_out;

    // workspace partition (~23 MB)
    float*          s0s1 = (float*)d_ws;                           // NTOT float2
    unsigned short* tcf  = (unsigned short*)(s0s1 + 2 * NTOT);     // NTOT*CC bf16
    unsigned short* fcf  = tcf + (size_t)NTOT * CC;                // NTOT*CC bf16
    unsigned short* W1p  = fcf + (size_t)NTOT * CC;                // CC*K1 bf16 (panels)
    unsigned short* W2p  = W1p + (size_t)CC * K1;                  // CC*K1 bf16 (panels)
    unsigned short* zp   = W2p + (size_t)CC * K1;                  // 1024 zeros
    float*          part = (float*)(zp + 1024);                    // NTOT x 6 fp32

    prep_kernel<<<(CC * K1 + 255) / 256, 256, 0, stream>>>(conv_w, adapt_w, W1p, W2p, zp);
    transpose_kernel<<<dim3(HWP / 64, 4, BB), 256, 0, stream>>>(feature, fcf);
    gemm1_kernel<<<dim3(NTOT / 64 * 2), 512, 0, stream>>>(
        W1p, fcf, conv_b, zp, loc_w, shape_w, tcf, part);
    combine_kernel<<<dim3(NTOT / 256), 256, 0, stream>>>(
        part, loc_b, shape_b, out, s0s1);
    gemm2_fused_kernel<<<dim3(NTOT / 32), 256, 0, stream>>>(
        W2p, tcf, s0s1, offset_w, cls_w, cls_b, bbox_w, bbox_b, out);
}

// Round 20
// 188.601 us; speedup vs baseline: 1.1189x; 1.0280x over previous
//
#include <hip/hip_runtime.h>
#include <hip/hip_bf16.h>

// Problem constants
#define BB 2
#define CC 256
#define HH 96
#define WW 96
#define HWP (HH*WW)        // 9216
#define NTOT (BB*HWP)      // 18432 flattened (b,p)
#define K1 2304            // 256*9, GEMM K for both convs
#define NKT 36             // K1/64 k-steps

// d_out layout: logits[2,1,96,96], bbox[2,4,96,96], shape[2,2,96,96], loc[2,1,96,96]
#define OUT_LOGITS 0
#define OUT_BBOX   (2*1*HWP)
#define OUT_SHAPE  (OUT_BBOX + 2*4*HWP)
#define OUT_LOC    (OUT_SHAPE + 2*2*HWP)

typedef __attribute__((ext_vector_type(8))) short short8v;   // 8 bf16 (4 VGPRs)
typedef __attribute__((ext_vector_type(4))) float f32x4;

// XCD-aware swizzles: contiguous slab of consecutive n-blocks per XCD.
__device__ __forceinline__ int xcd_swizzle288(int bx) {    // 288 = 8 x 36
    return (bx & 7) * 36 + (bx >> 3);
}
__device__ __forceinline__ int xcd_swizzle576(int bx) {    // 576 = 8 x 72
    return (bx & 7) * 72 + (bx >> 3);
}

__device__ __forceinline__ float bf2f(unsigned short u) {
    return __uint_as_float(((unsigned)u) << 16);
}
__device__ __forceinline__ unsigned short f2bf(float f) {
    unsigned u = __float_as_uint(f);
    u += 0x7FFFu + ((u >> 16) & 1u);           // round-to-nearest-even
    return (unsigned short)(u >> 16);
}

// ------- setup: prep (weights -> bf16 panels + zero page)  [blocks 0..2303]
//              + transpose (feature -> f_cf bf16 [b][p][c]) [blocks 2304..3455]
// R20: merged into ONE launch — independent work, previously serialized
// across a launch boundary.
#define PREP_BLOCKS 2304
__global__ __launch_bounds__(256) void setup_kernel(
    const float* __restrict__ conv_w, const float* __restrict__ adapt_w,
    const float* __restrict__ f,
    unsigned short* __restrict__ W1p, unsigned short* __restrict__ W2p,
    unsigned short* __restrict__ zp, unsigned short* __restrict__ fcf)
{
    __shared__ unsigned short tile[64][66];     // +2 pad (transpose path only)
    if (blockIdx.x < PREP_BLOCKS) {
        // ---- prep path (R18-exact math) ----
        const int t = blockIdx.x * 256 + threadIdx.x;
        if (t < 1024) zp[t] = 0;                // zero page (ws is re-poisoned!)
        if (t < CC * K1) {
            const int e = t & 7;
            {   // W1p
                const int s  = (t >> 3) & 1023;
                const int r  = t >> 13;         // cb*36+kt, [0,72)
                const int kt = r % 36, cb = r / 36;
                const int row = s & 127, kc = s >> 7;
                const int co = cb * 128 + row;
                const int k  = kt * 64 + kc * 8 + e;
                const int kk = k >> 8, ci = k & 255;
                W1p[t] = f2bf(conv_w[co * K1 + ci * 9 + kk]);
            }
            {   // W2p
                const int s  = (t >> 3) & 2047;
                const int kt = t >> 14;         // [0,36)
                const int row = s & 255, kc = s >> 8;
                const int k  = kt * 64 + kc * 8 + e;
                const int kk = k >> 8, ci = k & 255;
                W2p[t] = f2bf(adapt_w[row * K1 + ci * 9 + kk]);
            }
        }
    } else {
        // ---- transpose path (R12-exact: ushort4-vectorized store) ----
        const int bx2 = blockIdx.x - PREP_BLOCKS;
        const int px  = bx2 % 144, rest = bx2 / 144;
        const int cc  = rest & 3, b = rest >> 2;
        const int p0  = px * 64;
        const int tx = threadIdx.x & 63, ty = threadIdx.x >> 6;
#pragma unroll
        for (int ii = 0; ii < 16; ii++) {
            const int cl = ii * 4 + ty;
            tile[cl][tx] = f2bf(f[((size_t)b * CC + cc * 64 + cl) * HWP + p0 + tx]);
        }
        __syncthreads();
        const int tx4 = threadIdx.x & 15;       // c-quad index
        const int py  = threadIdx.x >> 4;       // pixel sub-index (0..15)
#pragma unroll
        for (int ii = 0; ii < 4; ii++) {
            const int pl = ii * 16 + py;
            ushort4 v;
            v.x = tile[tx4 * 4 + 0][pl];
            v.y = tile[tx4 * 4 + 1][pl];
            v.z = tile[tx4 * 4 + 2][pl];
            v.w = tile[tx4 * 4 + 3][pl];
            *(ushort4*)(fcf + ((size_t)(b * HWP + p0 + pl)) * CC + cc * 64 + tx4 * 4) = v;
        }
    }
}

// --------- GEMM1 + fused heads1 partials, 512 thr / 8 waves -----------------
// R19-exact (193.9 us proven): K-loop R13 (cb in bx&1, A-direct from L2,
// depth-1 B prefetch); epilogue computes loc/shape partial dots in fp32
// (per-thread dots -> quad shuffle -> LDS reduce) -> part[n][cb][3].
__global__ __launch_bounds__(512, 6) void gemm1_kernel(
    const unsigned short* __restrict__ W1p, const unsigned short* __restrict__ fcf,
    const float* __restrict__ bias, const unsigned short* __restrict__ zp,
    const float* __restrict__ loc_w, const float* __restrict__ shape_w,
    unsigned short* __restrict__ tcf, float* __restrict__ part)
{
    __shared__ short Bs[2][4096];               // 2 x 8 KB (XOR-swizzled)
    __shared__ float sm1[4][64][4];             // [wm][pixel][3 dots + pad] 4 KB
    const int tid  = threadIdx.x;
    const int lane = tid & 63, w = tid >> 6;    // w in [0,8)
    const int quad = lane >> 4, r15 = lane & 15;
    const int cb  = blockIdx.x & 1;             // interleaved co-half
    const int n0  = xcd_swizzle288(blockIdx.x >> 1) * 64;
    const int co0 = cb * 128;
    const int wm = w & 3, wn = w >> 2;          // co-quarter (32 rows), n-half

    // B staging geometry: thread -> (pixel pr, 8-ch chunk kc)
    const int pr = tid >> 3, kc = tid & 7;
    const int xsw = (pr * 8 + (kc ^ (pr & 7))) * 8;   // Bs write slot (shorts)
    const int nb = n0 + pr;
    const int b  = nb / HWP;
    const int p  = nb - b * HWP;
    const int y = p / WW, x = p % WW;
    const unsigned short* fb = fcf + (size_t)b * HWP * CC;

    f32x4 acc[2][2];
#pragma unroll
    for (int i = 0; i < 2; i++)
#pragma unroll
        for (int j = 0; j < 2; j++) acc[i][j] = (f32x4){0.f, 0.f, 0.f, 0.f};

    auto loadB = [&](int kt) -> short8v {
        const int kk  = kt >> 2;
        const int ci0 = (kt & 3) * 64;
        const int yy = y + kk / 3 - 1, xx = x + kk % 3 - 1;
        const bool ok = (yy >= 0) && (yy < HH) && (xx >= 0) && (xx < WW);
        const unsigned short* src = ok
            ? fb + (size_t)(yy * WW + xx) * CC + ci0 + kc * 8
            : zp;
        return *(const short8v*)src;
    };
    // A-fragment direct from global: slot = kchunk*128 + row within kt-panel.
    auto mma = [&](int buf, int kt) {
        const unsigned short* pnl = W1p + ((size_t)(cb * 36 + kt) * 1024) * 8;
#pragma unroll
        for (int ks = 0; ks < 2; ks++) {
            short8v a[2], bf[2];
            const int kchunk = ks * 4 + quad;
#pragma unroll
            for (int i = 0; i < 2; i++)
                a[i] = *(const short8v*)(pnl + (size_t)(kchunk * 128 + wm * 32 + i * 16 + r15) * 8);
#pragma unroll
            for (int j = 0; j < 2; j++) {
                const int row = wn * 32 + j * 16 + r15;
                bf[j] = *(const short8v*)&Bs[buf][(row * 8 + (kchunk ^ (row & 7))) * 8];
            }
#pragma unroll
            for (int i = 0; i < 2; i++)
#pragma unroll
                for (int j = 0; j < 2; j++)
                    acc[i][j] = __builtin_amdgcn_mfma_f32_16x16x32_bf16(a[i], bf[j], acc[i][j], 0, 0, 0);
        }
    };

    { short8v b0 = loadB(0); *(short8v*)&Bs[0][xsw] = b0; }
    __syncthreads();
    int cur = 0;
    for (int kt = 0; kt < NKT - 1; kt++) {
        const int nxt = cur ^ 1;
        short8v bn = loadB(kt + 1);             // -> regs, latency under MFMA
        mma(cur, kt);
        *(short8v*)&Bs[nxt][xsw] = bn;
        __syncthreads();
        cur = nxt;
    }
    mma(cur, NKT - 1);                          // peeled last tile

    // epilogue: bias + relu (fp32) -> tcf bf16, + loc/shape partial dots
    float pl[2] = {0.f, 0.f}, p0s[2] = {0.f, 0.f}, p1s[2] = {0.f, 0.f};
#pragma unroll
    for (int i = 0; i < 2; i++) {
        const int m = co0 + wm * 32 + i * 16 + quad * 4;
        const float b0 = bias[m], b1 = bias[m + 1], b2 = bias[m + 2], b3 = bias[m + 3];
        const float4 lw  = *(const float4*)(loc_w + m);
        const float4 s0w = *(const float4*)(shape_w + m);
        const float4 s1w = *(const float4*)(shape_w + CC + m);
#pragma unroll
        for (int j = 0; j < 2; j++) {
            const int n = n0 + wn * 32 + j * 16 + r15;
            const float t0 = fmaxf(acc[i][j][0] + b0, 0.f);
            const float t1 = fmaxf(acc[i][j][1] + b1, 0.f);
            const float t2 = fmaxf(acc[i][j][2] + b2, 0.f);
            const float t3 = fmaxf(acc[i][j][3] + b3, 0.f);
            ushort4 st;
            st.x = f2bf(t0); st.y = f2bf(t1); st.z = f2bf(t2); st.w = f2bf(t3);
            *(ushort4*)(tcf + (size_t)n * CC + m) = st;
            pl[j]  = fmaf(lw.x,  t0, fmaf(lw.y,  t1, fmaf(lw.z,  t2, fmaf(lw.w,  t3, pl[j]))));
            p0s[j] = fmaf(s0w.x, t0, fmaf(s0w.y, t1, fmaf(s0w.z, t2, fmaf(s0w.w, t3, p0s[j]))));
            p1s[j] = fmaf(s1w.x, t0, fmaf(s1w.y, t1, fmaf(s1w.z, t2, fmaf(s1w.w, t3, p1s[j]))));
        }
    }
    // reduce across quads (lanes share r15): xor 16, 32 sums all 4 quads
#pragma unroll
    for (int j = 0; j < 2; j++) {
#pragma unroll
        for (int off = 16; off <= 32; off <<= 1) {
            pl[j]  += __shfl_xor(pl[j],  off);
            p0s[j] += __shfl_xor(p0s[j], off);
            p1s[j] += __shfl_xor(p1s[j], off);
        }
    }
    if (quad == 0) {                            // lanes 0..15 hold reduced vals
#pragma unroll
        for (int j = 0; j < 2; j++) {
            const int pix = wn * 32 + j * 16 + r15;
            sm1[wm][pix][0] = pl[j];
            sm1[wm][pix][1] = p0s[j];
            sm1[wm][pix][2] = p1s[j];
        }
    }
    __syncthreads();
    if (tid < 64) {                             // one thread per pixel
        const int n = n0 + tid;
        const float a0 = sm1[0][tid][0] + sm1[1][tid][0] + sm1[2][tid][0] + sm1[3][tid][0];
        const float a1 = sm1[0][tid][1] + sm1[1][tid][1] + sm1[2][tid][1] + sm1[3][tid][1];
        const float a2 = sm1[0][tid][2] + sm1[1][tid][2] + sm1[2][tid][2] + sm1[3][tid][2];
        float* dst = part + (size_t)n * 6 + cb * 3;
        dst[0] = a0; dst[1] = a1; dst[2] = a2;
    }
}

// ---- fused GEMM2 + heads2 + combine, FULL-K, M=256 x N=32, 256 thr ---------
// R14-exact K-loop/epilogue. R20: combine folded in — sampler threads derive
// s01 from part (same adds/order as combine_kernel: pr[1]+pr[4]+shape_b[0],
// pr[2]+pr[5]+shape_b[1]); threads 0-31 write loc/shape outputs at entry.
__global__ __launch_bounds__(256, 3) void gemm2_fused_kernel(
    const unsigned short* __restrict__ W2p, const unsigned short* __restrict__ tcf,
    const float* __restrict__ part, const float* __restrict__ offset_w,
    const float* __restrict__ loc_b, const float* __restrict__ shape_b,
    const float* __restrict__ cls_w, const float* __restrict__ cls_b,
    const float* __restrict__ bbox_w, const float* __restrict__ bbox_b,
    float* __restrict__ out)
{
    __shared__ short Bs[2][2048];               // 2 x 4 KB (32 rows x 8 chunks, XOR)
    __shared__ float sm[4][32][6];              // [wave][n][5 heads], +1 pad
    const int tid  = threadIdx.x;
    const int lane = tid & 63, wm = tid >> 6;   // 4 waves, wm = co-quarter (64 rows)
    const int quad = lane >> 4, r15 = lane & 15;
    const int n0  = xcd_swizzle576(blockIdx.x) * 32;
    const int b   = n0 / HWP;                   // whole block in one batch
    const unsigned short* tb = tcf + (size_t)b * HWP * CC;

    // sampler mapping: thread -> pixel pr (0..31), 8-ch chunk kc (one px/thread)
    const int pr = tid >> 3, kc = tid & 7;
    const int xsw = (pr * 8 + (kc ^ (pr & 7))) * 8;   // Bs write slot (shorts)
    const int nb = n0 + pr;
    const int p  = nb - b * HWP;
    const int y = p / WW, x = p % WW;
    // s01 from part (combine math, same order)
    const float* prt = part + (size_t)nb * 6;
    const float2 s01 = make_float2(prt[1] + prt[4] + shape_b[0],
                                   prt[2] + prt[5] + shape_b[1]);

    // fold of combine_kernel: write loc/shape outputs (one thread per pixel)
    if (tid < 32) {
        const int n = n0 + tid;
        const int bb = n / HWP, pp = n - bb * HWP;
        const float* pq = part + (size_t)n * 6;
        out[OUT_LOC + n] = pq[0] + pq[3] + loc_b[0];
        out[OUT_SHAPE + (bb * 2 + 0) * HWP + pp] = pq[1] + pq[4] + shape_b[0];
        out[OUT_SHAPE + (bb * 2 + 1) * HWP + pp] = pq[2] + pq[5] + shape_b[1];
    }

    f32x4 acc[4][2];
#pragma unroll
    for (int i = 0; i < 4; i++)
#pragma unroll
        for (int j = 0; j < 2; j++) acc[i][j] = (f32x4){0.f, 0.f, 0.f, 0.f};

    struct Samp { short8v v00, v01, v10, v11; float w00, w01, w10, w11; };
    struct AF2 { short8v c0i0, c0i1, c0i2, c0i3, c1i0, c1i1, c1i2, c1i3; };

    auto loadA = [&](int kt) -> AF2 {           // panel -> regs (L2-resident)
        const unsigned short* pnl = W2p + ((size_t)kt * 2048) * 8;
        const int b0 = quad * 256 + wm * 64 + r15;
        const int b1 = (4 + quad) * 256 + wm * 64 + r15;
        AF2 r;
        r.c0i0 = *(const short8v*)(pnl + (size_t)(b0 +  0) * 8);
        r.c0i1 = *(const short8v*)(pnl + (size_t)(b0 + 16) * 8);
        r.c0i2 = *(const short8v*)(pnl + (size_t)(b0 + 32) * 8);
        r.c0i3 = *(const short8v*)(pnl + (size_t)(b0 + 48) * 8);
        r.c1i0 = *(const short8v*)(pnl + (size_t)(b1 +  0) * 8);
        r.c1i1 = *(const short8v*)(pnl + (size_t)(b1 + 16) * 8);
        r.c1i2 = *(const short8v*)(pnl + (size_t)(b1 + 32) * 8);
        r.c1i3 = *(const short8v*)(pnl + (size_t)(b1 + 48) * 8);
        return r;
    };
    // issue phase: address math + 4 gathers into regs (R9-verbatim per-pixel math)
    auto sampIssue = [&](int kt) -> Samp {
        Samp s;
        const int kk = kt >> 2, g = kt & 3;
        const int o_dy = (g * 9 + kk) * 2, o_dx = o_dy + 1;
        const float dy = fmaf(offset_w[o_dy * 2], s01.x, offset_w[o_dy * 2 + 1] * s01.y);
        const float dx = fmaf(offset_w[o_dx * 2], s01.x, offset_w[o_dx * 2 + 1] * s01.y);
        const float py = (float)(y + kk / 3 - 1) + dy;
        const float px = (float)(x + kk % 3 - 1) + dx;
        const float y0f = floorf(py), x0f = floorf(px);
        const float wy = py - y0f, wx = px - x0f;
        const int y0 = (int)y0f, x0 = (int)x0f;
        const int y1 = y0 + 1, x1 = x0 + 1;
        const bool vy0 = (y0 >= 0) && (y0 < HH), vy1 = (y1 >= 0) && (y1 < HH);
        const bool vx0 = (x0 >= 0) && (x0 < WW), vx1 = (x1 >= 0) && (x1 < WW);
        const int y0c = min(max(y0, 0), HH - 1), y1c = min(max(y1, 0), HH - 1);
        const int x0c = min(max(x0, 0), WW - 1), x1c = min(max(x1, 0), WW - 1);
        s.w00 = (vy0 && vx0) ? (1.f - wy) * (1.f - wx) : 0.f;
        s.w01 = (vy0 && vx1) ? (1.f - wy) * wx         : 0.f;
        s.w10 = (vy1 && vx0) ? wy * (1.f - wx)         : 0.f;
        s.w11 = (vy1 && vx1) ? wy * wx                 : 0.f;
        const int ch = g * 64 + kc * 8;
        s.v00 = *(const short8v*)(tb + (size_t)(y0c * WW + x0c) * CC + ch);
        s.v01 = *(const short8v*)(tb + (size_t)(y0c * WW + x1c) * CC + ch);
        s.v10 = *(const short8v*)(tb + (size_t)(y1c * WW + x0c) * CC + ch);
        s.v11 = *(const short8v*)(tb + (size_t)(y1c * WW + x1c) * CC + ch);
        return s;
    };
    // finish phase: bilinear blend + bf16 round + swizzled ds_write
    auto sampFinish = [&](const Samp& s, int buf) {
        short8v r;
#pragma unroll
        for (int e = 0; e < 8; e++) {
            float val = s.w00 * bf2f((unsigned short)s.v00[e]);
            val = fmaf(s.w01, bf2f((unsigned short)s.v01[e]), val);
            val = fmaf(s.w10, bf2f((unsigned short)s.v10[e]), val);
            val = fmaf(s.w11, bf2f((unsigned short)s.v11[e]), val);
            r[e] = (short)f2bf(val);
        }
        *(short8v*)&Bs[buf][xsw] = r;
    };
    auto mma = [&](int buf, const AF2& a) {
        {   // ks = 0, kchunk = quad
            const int kchunk = quad;
            const int row0 = r15, row1 = 16 + r15;
            short8v bf0 = *(const short8v*)&Bs[buf][(row0 * 8 + (kchunk ^ (row0 & 7))) * 8];
            short8v bf1 = *(const short8v*)&Bs[buf][(row1 * 8 + (kchunk ^ (row1 & 7))) * 8];
            acc[0][0] = __builtin_amdgcn_mfma_f32_16x16x32_bf16(a.c0i0, bf0, acc[0][0], 0, 0, 0);
            acc[0][1] = __builtin_amdgcn_mfma_f32_16x16x32_bf16(a.c0i0, bf1, acc[0][1], 0, 0, 0);
            acc[1][0] = __builtin_amdgcn_mfma_f32_16x16x32_bf16(a.c0i1, bf0, acc[1][0], 0, 0, 0);
            acc[1][1] = __builtin_amdgcn_mfma_f32_16x16x32_bf16(a.c0i1, bf1, acc[1][1], 0, 0, 0);
            acc[2][0] = __builtin_amdgcn_mfma_f32_16x16x32_bf16(a.c0i2, bf0, acc[2][0], 0, 0, 0);
            acc[2][1] = __builtin_amdgcn_mfma_f32_16x16x32_bf16(a.c0i2, bf1, acc[2][1], 0, 0, 0);
            acc[3][0] = __builtin_amdgcn_mfma_f32_16x16x32_bf16(a.c0i3, bf0, acc[3][0], 0, 0, 0);
            acc[3][1] = __builtin_amdgcn_mfma_f32_16x16x32_bf16(a.c0i3, bf1, acc[3][1], 0, 0, 0);
        }
        {   // ks = 1, kchunk = 4 + quad
            const int kchunk = 4 + quad;
            const int row0 = r15, row1 = 16 + r15;
            short8v bf0 = *(const short8v*)&Bs[buf][(row0 * 8 + (kchunk ^ (row0 & 7))) * 8];
            short8v bf1 = *(const short8v*)&Bs[buf][(row1 * 8 + (kchunk ^ (row1 & 7))) * 8];
            acc[0][0] = __builtin_amdgcn_mfma_f32_16x16x32_bf16(a.c1i0, bf0, acc[0][0], 0, 0, 0);
            acc[0][1] = __builtin_amdgcn_mfma_f32_16x16x32_bf16(a.c1i0, bf1, acc[0][1], 0, 0, 0);
            acc[1][0] = __builtin_amdgcn_mfma_f32_16x16x32_bf16(a.c1i1, bf0, acc[1][0], 0, 0, 0);
            acc[1][1] = __builtin_amdgcn_mfma_f32_16x16x32_bf16(a.c1i1, bf1, acc[1][1], 0, 0, 0);
            acc[2][0] = __builtin_amdgcn_mfma_f32_16x16x32_bf16(a.c1i2, bf0, acc[2][0], 0, 0, 0);
            acc[2][1] = __builtin_amdgcn_mfma_f32_16x16x32_bf16(a.c1i2, bf1, acc[2][1], 0, 0, 0);
            acc[3][0] = __builtin_amdgcn_mfma_f32_16x16x32_bf16(a.c1i3, bf0, acc[3][0], 0, 0, 0);
            acc[3][1] = __builtin_amdgcn_mfma_f32_16x16x32_bf16(a.c1i3, bf1, acc[3][1], 0, 0, 0);
        }
    };

    // ---- K-loop over all 36 kts (full-K), 2x-unrolled, named afA/afB ----
    AF2 afA = loadA(0), afB;
    { Samp s = sampIssue(0); sampFinish(s, 0); }
    __syncthreads();
    int cur = 0;
    for (int k2 = 0; k2 < (NKT - 2) / 2; k2++) {
        const int kt = 2 * k2;
        {   // step kt: consume afA, prefetch afB = A(kt+1)
            const int nxt = cur ^ 1;
            afB = loadA(kt + 1);
            Samp s = sampIssue(kt + 1);
            mma(cur, afA);
            sampFinish(s, nxt);
            __syncthreads();
            cur = nxt;
        }
        {   // step kt+1: consume afB, prefetch afA = A(kt+2)
            const int nxt = cur ^ 1;
            afA = loadA(kt + 2);
            Samp s = sampIssue(kt + 2);
            mma(cur, afB);
            sampFinish(s, nxt);
            __syncthreads();
            cur = nxt;
        }
    }
    {   // step NKT-2 = 34: consume afA, prefetch afB = A(35)
        const int nxt = cur ^ 1;
        afB = loadA(NKT - 1);
        Samp s = sampIssue(NKT - 1);
        mma(cur, afA);
        sampFinish(s, nxt);
        __syncthreads();
        cur = nxt;
    }
    mma(cur, afB);                              // step 35

    // ---- fused epilogue: relu + cls/bbox dots, cross-wave reduce ----
    float pc[2]  = {0.f, 0.f};
    float pb0[2] = {0.f, 0.f}, pb1[2] = {0.f, 0.f};
    float pb2[2] = {0.f, 0.f}, pb3[2] = {0.f, 0.f};
#pragma unroll
    for (int i = 0; i < 4; i++) {
        const int m = wm * 64 + i * 16 + quad * 4;
        const float4 cw  = *(const float4*)(cls_w + m);
        const float4 b0w = *(const float4*)(bbox_w + m);
        const float4 b1w = *(const float4*)(bbox_w + CC + m);
        const float4 b2w = *(const float4*)(bbox_w + 2 * CC + m);
        const float4 b3w = *(const float4*)(bbox_w + 3 * CC + m);
#pragma unroll
        for (int j = 0; j < 2; j++) {
            const float t0 = fmaxf(acc[i][j][0], 0.f);
            const float t1 = fmaxf(acc[i][j][1], 0.f);
            const float t2 = fmaxf(acc[i][j][2], 0.f);
            const float t3 = fmaxf(acc[i][j][3], 0.f);
            pc[j]  = fmaf(cw.x,  t0, fmaf(cw.y,  t1, fmaf(cw.z,  t2, fmaf(cw.w,  t3, pc[j]))));
            pb0[j] = fmaf(b0w.x, t0, fmaf(b0w.y, t1, fmaf(b0w.z, t2, fmaf(b0w.w, t3, pb0[j]))));
            pb1[j] = fmaf(b1w.x, t0, fmaf(b1w.y, t1, fmaf(b1w.z, t2, fmaf(b1w.w, t3, pb1[j]))));
            pb2[j] = fmaf(b2w.x, t0, fmaf(b2w.y, t1, fmaf(b2w.z, t2, fmaf(b2w.w, t3, pb2[j]))));
            pb3[j] = fmaf(b3w.x, t0, fmaf(b3w.y, t1, fmaf(b3w.z, t2, fmaf(b3w.w, t3, pb3[j]))));
        }
    }
    // reduce across quad (lanes r15 + 16*quad): xor 16, 32 sums all 4 quads
#pragma unroll
    for (int j = 0; j < 2; j++) {
#pragma unroll
        for (int off = 16; off <= 32; off <<= 1) {
            pc[j]  += __shfl_xor(pc[j],  off);
            pb0[j] += __shfl_xor(pb0[j], off);
            pb1[j] += __shfl_xor(pb1[j], off);
            pb2[j] += __shfl_xor(pb2[j], off);
            pb3[j] += __shfl_xor(pb3[j], off);
        }
    }
    if (quad == 0) {                            // lanes 0..15 hold reduced vals
#pragma unroll
        for (int j = 0; j < 2; j++) {
            const int nl = j * 16 + r15;
            sm[wm][nl][0] = pc[j];
            sm[wm][nl][1] = pb0[j];
            sm[wm][nl][2] = pb1[j];
            sm[wm][nl][3] = pb2[j];
            sm[wm][nl][4] = pb3[j];
        }
    }
    __syncthreads();
    if (tid < 32) {                             // one thread per pixel
        const int n = n0 + tid;
        const int bb = n / HWP, pp = n - bb * HWP;
        const float vc = sm[0][tid][0] + sm[1][tid][0] + sm[2][tid][0] + sm[3][tid][0];
        const float v0 = sm[0][tid][1] + sm[1][tid][1] + sm[2][tid][1] + sm[3][tid][1];
        const float v1 = sm[0][tid][2] + sm[1][tid][2] + sm[2][tid][2] + sm[3][tid][2];
        const float v2 = sm[0][tid][3] + sm[1][tid][3] + sm[2][tid][3] + sm[3][tid][3];
        const float v3 = sm[0][tid][4] + sm[1][tid][4] + sm[2][tid][4] + sm[3][tid][4];
        out[OUT_LOGITS + n] = vc + cls_b[0];
        out[OUT_BBOX + (bb * 4 + 0) * HWP + pp] = v0 + bbox_b[0];
        out[OUT_BBOX + (bb * 4 + 1) * HWP + pp] = v1 + bbox_b[1];
        out[OUT_BBOX + (bb * 4 + 2) * HWP + pp] = v2 + bbox_b[2];
        out[OUT_BBOX + (bb * 4 + 3) * HWP + pp] = v3 + bbox_b[3];
    }
}

// ----------------------------------------------------------------------------
extern "C" void kernel_launch(void* const* d_in, const int* in_sizes, int n_in,
                              void* d_out, int out_size, void* d_ws, size_t ws_size,
                              hipStream_t stream)
{
    const float* feature  = (const float*)d_in[0];
    const float* conv_w   = (const float*)d_in[1];
    const float* conv_b   = (const float*)d_in[2];
    const float* loc_w    = (const float*)d_in[3];
    const float* loc_b    = (const float*)d_in[4];
    const float* shape_w  = (const float*)d_in[5];
    const float* shape_b  = (const float*)d_in[6];
    const float* offset_w = (const float*)d_in[7];
    const float* adapt_w  = (const float*)d_in[8];
    const float* cls_w    = (const float*)d_in[9];
    const float* cls_b    = (const float*)d_in[10];
    const float* bbox_w   = (const float*)d_in[11];
    const float* bbox_b   = (const float*)d_in[12];
    float* out = (float*)d_out;

    // workspace partition (~23 MB)
    unsigned short* tcf  = (unsigned short*)d_ws;                  // NTOT*CC bf16
    unsigned short* fcf  = tcf + (size_t)NTOT * CC;                // NTOT*CC bf16
    unsigned short* W1p  = fcf + (size_t)NTOT * CC;                // CC*K1 bf16 (panels)
    unsigned short* W2p  = W1p + (size_t)CC * K1;                  // CC*K1 bf16 (panels)
    unsigned short* zp   = W2p + (size_t)CC * K1;                  // 1024 zeros
    float*          part = (float*)(zp + 1024);                    // NTOT x 6 fp32

    setup_kernel<<<dim3(PREP_BLOCKS + 1152), 256, 0, stream>>>(
        conv_w, adapt_w, feature, W1p, W2p, zp, fcf);
    gemm1_kernel<<<dim3(NTOT / 64 * 2), 512, 0, stream>>>(
        W1p, fcf, conv_b, zp, loc_w, shape_w, tcf, part);
    gemm2_fused_kernel<<<dim3(NTOT / 32), 256, 0, stream>>>(
        W2p, tcf, part, offset_w, loc_b, shape_b, cls_w, cls_b, bbox_w, bbox_b, out);
}

// Round 21
// 180.702 us; speedup vs baseline: 1.1678x; 1.0437x over previous
//
#include <hip/hip_runtime.h>
#include <hip/hip_bf16.h>

// Problem constants
#define BB 2
#define CC 256
#define HH 96
#define WW 96
#define HWP (HH*WW)        // 9216
#define NTOT (BB*HWP)      // 18432 flattened (b,p)
#define K1 2304            // 256*9, GEMM K for both convs
#define NKT 36             // K1/64 k-steps

// d_out layout: logits[2,1,96,96], bbox[2,4,96,96], shape[2,2,96,96], loc[2,1,96,96]
#define OUT_LOGITS 0
#define OUT_BBOX   (2*1*HWP)
#define OUT_SHAPE  (OUT_BBOX + 2*4*HWP)
#define OUT_LOC    (OUT_SHAPE + 2*2*HWP)

typedef __attribute__((ext_vector_type(8))) short short8v;   // 8 bf16 (4 VGPRs)
typedef __attribute__((ext_vector_type(4))) float f32x4;

// XCD-aware swizzle: contiguous slab of consecutive n-blocks per XCD.
__device__ __forceinline__ int xcd_swizzle576(int bx) {    // 576 = 8 x 72
    return (bx & 7) * 72 + (bx >> 3);
}

__device__ __forceinline__ float bf2f(unsigned short u) {
    return __uint_as_float(((unsigned)u) << 16);
}
__device__ __forceinline__ unsigned short f2bf(float f) {
    unsigned u = __float_as_uint(f);
    u += 0x7FFFu + ((u >> 16) & 1u);           // round-to-nearest-even
    return (unsigned short)(u >> 16);
}

// ------- setup: prep (weights -> bf16 panels + zero page)  [blocks 0..2303]
//              + transpose (feature -> f_cf bf16 [b][p][c]) [blocks 2304..3455]
// R20-proven: merged into ONE launch.
#define PREP_BLOCKS 2304
__global__ __launch_bounds__(256) void setup_kernel(
    const float* __restrict__ conv_w, const float* __restrict__ adapt_w,
    const float* __restrict__ f,
    unsigned short* __restrict__ W1p, unsigned short* __restrict__ W2p,
    unsigned short* __restrict__ zp, unsigned short* __restrict__ fcf)
{
    __shared__ unsigned short tile[64][66];     // +2 pad (transpose path only)
    if (blockIdx.x < PREP_BLOCKS) {
        // ---- prep path ----
        const int t = blockIdx.x * 256 + threadIdx.x;
        if (t < 1024) zp[t] = 0;                // zero page (ws is re-poisoned!)
        if (t < CC * K1) {
            const int e = t & 7;
            {   // W1p
                const int s  = (t >> 3) & 1023;
                const int r  = t >> 13;         // cb*36+kt, [0,72)
                const int kt = r % 36, cb = r / 36;
                const int row = s & 127, kc = s >> 7;
                const int co = cb * 128 + row;
                const int k  = kt * 64 + kc * 8 + e;
                const int kk = k >> 8, ci = k & 255;
                W1p[t] = f2bf(conv_w[co * K1 + ci * 9 + kk]);
            }
            {   // W2p
                const int s  = (t >> 3) & 2047;
                const int kt = t >> 14;         // [0,36)
                const int row = s & 255, kc = s >> 8;
                const int k  = kt * 64 + kc * 8 + e;
                const int kk = k >> 8, ci = k & 255;
                W2p[t] = f2bf(adapt_w[row * K1 + ci * 9 + kk]);
            }
        }
    } else {
        // ---- transpose path (R12-exact: ushort4-vectorized store) ----
        const int bx2 = blockIdx.x - PREP_BLOCKS;
        const int px  = bx2 % 144, rest = bx2 / 144;
        const int cc  = rest & 3, b = rest >> 2;
        const int p0  = px * 64;
        const int tx = threadIdx.x & 63, ty = threadIdx.x >> 6;
#pragma unroll
        for (int ii = 0; ii < 16; ii++) {
            const int cl = ii * 4 + ty;
            tile[cl][tx] = f2bf(f[((size_t)b * CC + cc * 64 + cl) * HWP + p0 + tx]);
        }
        __syncthreads();
        const int tx4 = threadIdx.x & 15;       // c-quad index
        const int py  = threadIdx.x >> 4;       // pixel sub-index (0..15)
#pragma unroll
        for (int ii = 0; ii < 4; ii++) {
            const int pl = ii * 16 + py;
            ushort4 v;
            v.x = tile[tx4 * 4 + 0][pl];
            v.y = tile[tx4 * 4 + 1][pl];
            v.z = tile[tx4 * 4 + 2][pl];
            v.w = tile[tx4 * 4 + 3][pl];
            *(ushort4*)(fcf + ((size_t)(b * HWP + p0 + pl)) * CC + cc * 64 + tx4 * 4) = v;
        }
    }
}

// --------- GEMM1 + fused heads1 partials, M=128(cb) x N=32, 256 thr ---------
// R21: gemm2's PROVEN block shape ported to gemm1 — 4 waves, N=32, grid 2304
// = 9 independent blocks/CU (4x the old 8-wave shape; R8/R17 lesson: only
// independent blocks add TLP). Per-wave MFMA/kt unchanged (8). Bs = gemm2's
// exact 32-row x 8-chunk XOR layout. K-loop mechanics and epilogue math
// identical to R19/R20 (fp32 relu -> tcf bf16 + loc/shape partial dots).
__global__ __launch_bounds__(256, 3) void gemm1_kernel(
    const unsigned short* __restrict__ W1p, const unsigned short* __restrict__ fcf,
    const float* __restrict__ bias, const unsigned short* __restrict__ zp,
    const float* __restrict__ loc_w, const float* __restrict__ shape_w,
    unsigned short* __restrict__ tcf, float* __restrict__ part)
{
    __shared__ short Bs[2][2048];               // 2 x 4 KB (32 rows x 8 chunks, XOR)
    __shared__ float sm1[4][32][4];             // [wm][pixel][3 dots + pad] 2 KB
    const int tid  = threadIdx.x;
    const int lane = tid & 63, wm = tid >> 6;   // 4 waves, wm = co-quarter (32 rows)
    const int quad = lane >> 4, r15 = lane & 15;
    const int cb  = blockIdx.x & 1;             // interleaved co-half
    const int n0  = xcd_swizzle576(blockIdx.x >> 1) * 32;
    const int co0 = cb * 128;

    // B staging geometry: thread -> (pixel pr 0..31, 8-ch chunk kc)
    const int pr = tid >> 3, kc = tid & 7;
    const int xsw = (pr * 8 + (kc ^ (pr & 7))) * 8;   // Bs write slot (shorts)
    const int nb = n0 + pr;
    const int b  = nb / HWP;
    const int p  = nb - b * HWP;
    const int y = p / WW, x = p % WW;
    const unsigned short* fb = fcf + (size_t)b * HWP * CC;

    f32x4 acc[2][2];                            // [i: co 16-row][j: px 16-col]
#pragma unroll
    for (int i = 0; i < 2; i++)
#pragma unroll
        for (int j = 0; j < 2; j++) acc[i][j] = (f32x4){0.f, 0.f, 0.f, 0.f};

    auto loadB = [&](int kt) -> short8v {
        const int kk  = kt >> 2;
        const int ci0 = (kt & 3) * 64;
        const int yy = y + kk / 3 - 1, xx = x + kk % 3 - 1;
        const bool ok = (yy >= 0) && (yy < HH) && (xx >= 0) && (xx < WW);
        const unsigned short* src = ok
            ? fb + (size_t)(yy * WW + xx) * CC + ci0 + kc * 8
            : zp;
        return *(const short8v*)src;
    };
    // A-fragment direct from global: slot = kchunk*128 + row within kt-panel.
    auto mma = [&](int buf, int kt) {
        const unsigned short* pnl = W1p + ((size_t)(cb * 36 + kt) * 1024) * 8;
#pragma unroll
        for (int ks = 0; ks < 2; ks++) {
            short8v a[2], bf[2];
            const int kchunk = ks * 4 + quad;
#pragma unroll
            for (int i = 0; i < 2; i++)
                a[i] = *(const short8v*)(pnl + (size_t)(kchunk * 128 + wm * 32 + i * 16 + r15) * 8);
#pragma unroll
            for (int j = 0; j < 2; j++) {
                const int row = j * 16 + r15;
                bf[j] = *(const short8v*)&Bs[buf][(row * 8 + (kchunk ^ (row & 7))) * 8];
            }
#pragma unroll
            for (int i = 0; i < 2; i++)
#pragma unroll
                for (int j = 0; j < 2; j++)
                    acc[i][j] = __builtin_amdgcn_mfma_f32_16x16x32_bf16(a[i], bf[j], acc[i][j], 0, 0, 0);
        }
    };

    { short8v b0 = loadB(0); *(short8v*)&Bs[0][xsw] = b0; }
    __syncthreads();
    int cur = 0;
    for (int kt = 0; kt < NKT - 1; kt++) {
        const int nxt = cur ^ 1;
        short8v bn = loadB(kt + 1);             // -> regs, latency under MFMA
        mma(cur, kt);
        *(short8v*)&Bs[nxt][xsw] = bn;
        __syncthreads();
        cur = nxt;
    }
    mma(cur, NKT - 1);                          // peeled last tile

    // epilogue: bias + relu (fp32) -> tcf bf16, + loc/shape partial dots
    float pl[2] = {0.f, 0.f}, p0s[2] = {0.f, 0.f}, p1s[2] = {0.f, 0.f};
#pragma unroll
    for (int i = 0; i < 2; i++) {
        const int m = co0 + wm * 32 + i * 16 + quad * 4;
        const float b0 = bias[m], b1 = bias[m + 1], b2 = bias[m + 2], b3 = bias[m + 3];
        const float4 lw  = *(const float4*)(loc_w + m);
        const float4 s0w = *(const float4*)(shape_w + m);
        const float4 s1w = *(const float4*)(shape_w + CC + m);
#pragma unroll
        for (int j = 0; j < 2; j++) {
            const int n = n0 + j * 16 + r15;
            const float t0 = fmaxf(acc[i][j][0] + b0, 0.f);
            const float t1 = fmaxf(acc[i][j][1] + b1, 0.f);
            const float t2 = fmaxf(acc[i][j][2] + b2, 0.f);
            const float t3 = fmaxf(acc[i][j][3] + b3, 0.f);
            ushort4 st;
            st.x = f2bf(t0); st.y = f2bf(t1); st.z = f2bf(t2); st.w = f2bf(t3);
            *(ushort4*)(tcf + (size_t)n * CC + m) = st;
            pl[j]  = fmaf(lw.x,  t0, fmaf(lw.y,  t1, fmaf(lw.z,  t2, fmaf(lw.w,  t3, pl[j]))));
            p0s[j] = fmaf(s0w.x, t0, fmaf(s0w.y, t1, fmaf(s0w.z, t2, fmaf(s0w.w, t3, p0s[j]))));
            p1s[j] = fmaf(s1w.x, t0, fmaf(s1w.y, t1, fmaf(s1w.z, t2, fmaf(s1w.w, t3, p1s[j]))));
        }
    }
    // reduce across quads (lanes share r15): xor 16, 32 sums all 4 quads
#pragma unroll
    for (int j = 0; j < 2; j++) {
#pragma unroll
        for (int off = 16; off <= 32; off <<= 1) {
            pl[j]  += __shfl_xor(pl[j],  off);
            p0s[j] += __shfl_xor(p0s[j], off);
            p1s[j] += __shfl_xor(p1s[j], off);
        }
    }
    if (quad == 0) {                            // lanes 0..15 hold reduced vals
#pragma unroll
        for (int j = 0; j < 2; j++) {
            const int pix = j * 16 + r15;
            sm1[wm][pix][0] = pl[j];
            sm1[wm][pix][1] = p0s[j];
            sm1[wm][pix][2] = p1s[j];
        }
    }
    __syncthreads();
    if (tid < 32) {                             // one thread per pixel
        const int n = n0 + tid;
        const float a0 = sm1[0][tid][0] + sm1[1][tid][0] + sm1[2][tid][0] + sm1[3][tid][0];
        const float a1 = sm1[0][tid][1] + sm1[1][tid][1] + sm1[2][tid][1] + sm1[3][tid][1];
        const float a2 = sm1[0][tid][2] + sm1[1][tid][2] + sm1[2][tid][2] + sm1[3][tid][2];
        float* dst = part + (size_t)n * 6 + cb * 3;
        dst[0] = a0; dst[1] = a1; dst[2] = a2;
    }
}

// ---- fused GEMM2 + heads2 + combine, FULL-K, M=256 x N=32, 256 thr ---------
// R20-exact (188.6 us proven): full-K, A-reg-prefetch (named-member struct),
// depth-1 sampler, one __syncthreads per kt; combine folded in (s01 from
// part); fused cls/bbox epilogue.
__global__ __launch_bounds__(256, 3) void gemm2_fused_kernel(
    const unsigned short* __restrict__ W2p, const unsigned short* __restrict__ tcf,
    const float* __restrict__ part, const float* __restrict__ offset_w,
    const float* __restrict__ loc_b, const float* __restrict__ shape_b,
    const float* __restrict__ cls_w, const float* __restrict__ cls_b,
    const float* __restrict__ bbox_w, const float* __restrict__ bbox_b,
    float* __restrict__ out)
{
    __shared__ short Bs[2][2048];               // 2 x 4 KB (32 rows x 8 chunks, XOR)
    __shared__ float sm[4][32][6];              // [wave][n][5 heads], +1 pad
    const int tid  = threadIdx.x;
    const int lane = tid & 63, wm = tid >> 6;   // 4 waves, wm = co-quarter (64 rows)
    const int quad = lane >> 4, r15 = lane & 15;
    const int n0  = xcd_swizzle576(blockIdx.x) * 32;
    const int b   = n0 / HWP;                   // whole block in one batch
    const unsigned short* tb = tcf + (size_t)b * HWP * CC;

    // sampler mapping: thread -> pixel pr (0..31), 8-ch chunk kc (one px/thread)
    const int pr = tid >> 3, kc = tid & 7;
    const int xsw = (pr * 8 + (kc ^ (pr & 7))) * 8;   // Bs write slot (shorts)
    const int nb = n0 + pr;
    const int p  = nb - b * HWP;
    const int y = p / WW, x = p % WW;
    // s01 from part (combine math, same order)
    const float* prt = part + (size_t)nb * 6;
    const float2 s01 = make_float2(prt[1] + prt[4] + shape_b[0],
                                   prt[2] + prt[5] + shape_b[1]);

    // fold of combine_kernel: write loc/shape outputs (one thread per pixel)
    if (tid < 32) {
        const int n = n0 + tid;
        const int bb = n / HWP, pp = n - bb * HWP;
        const float* pq = part + (size_t)n * 6;
        out[OUT_LOC + n] = pq[0] + pq[3] + loc_b[0];
        out[OUT_SHAPE + (bb * 2 + 0) * HWP + pp] = pq[1] + pq[4] + shape_b[0];
        out[OUT_SHAPE + (bb * 2 + 1) * HWP + pp] = pq[2] + pq[5] + shape_b[1];
    }

    f32x4 acc[4][2];
#pragma unroll
    for (int i = 0; i < 4; i++)
#pragma unroll
        for (int j = 0; j < 2; j++) acc[i][j] = (f32x4){0.f, 0.f, 0.f, 0.f};

    struct Samp { short8v v00, v01, v10, v11; float w00, w01, w10, w11; };
    struct AF2 { short8v c0i0, c0i1, c0i2, c0i3, c1i0, c1i1, c1i2, c1i3; };

    auto loadA = [&](int kt) -> AF2 {           // panel -> regs (L2-resident)
        const unsigned short* pnl = W2p + ((size_t)kt * 2048) * 8;
        const int b0 = quad * 256 + wm * 64 + r15;
        const int b1 = (4 + quad) * 256 + wm * 64 + r15;
        AF2 r;
        r.c0i0 = *(const short8v*)(pnl + (size_t)(b0 +  0) * 8);
        r.c0i1 = *(const short8v*)(pnl + (size_t)(b0 + 16) * 8);
        r.c0i2 = *(const short8v*)(pnl + (size_t)(b0 + 32) * 8);
        r.c0i3 = *(const short8v*)(pnl + (size_t)(b0 + 48) * 8);
        r.c1i0 = *(const short8v*)(pnl + (size_t)(b1 +  0) * 8);
        r.c1i1 = *(const short8v*)(pnl + (size_t)(b1 + 16) * 8);
        r.c1i2 = *(const short8v*)(pnl + (size_t)(b1 + 32) * 8);
        r.c1i3 = *(const short8v*)(pnl + (size_t)(b1 + 48) * 8);
        return r;
    };
    // issue phase: address math + 4 gathers into regs (R9-verbatim per-pixel math)
    auto sampIssue = [&](int kt) -> Samp {
        Samp s;
        const int kk = kt >> 2, g = kt & 3;
        const int o_dy = (g * 9 + kk) * 2, o_dx = o_dy + 1;
        const float dy = fmaf(offset_w[o_dy * 2], s01.x, offset_w[o_dy * 2 + 1] * s01.y);
        const float dx = fmaf(offset_w[o_dx * 2], s01.x, offset_w[o_dx * 2 + 1] * s01.y);
        const float py = (float)(y + kk / 3 - 1) + dy;
        const float px = (float)(x + kk % 3 - 1) + dx;
        const float y0f = floorf(py), x0f = floorf(px);
        const float wy = py - y0f, wx = px - x0f;
        const int y0 = (int)y0f, x0 = (int)x0f;
        const int y1 = y0 + 1, x1 = x0 + 1;
        const bool vy0 = (y0 >= 0) && (y0 < HH), vy1 = (y1 >= 0) && (y1 < HH);
        const bool vx0 = (x0 >= 0) && (x0 < WW), vx1 = (x1 >= 0) && (x1 < WW);
        const int y0c = min(max(y0, 0), HH - 1), y1c = min(max(y1, 0), HH - 1);
        const int x0c = min(max(x0, 0), WW - 1), x1c = min(max(x1, 0), WW - 1);
        s.w00 = (vy0 && vx0) ? (1.f - wy) * (1.f - wx) : 0.f;
        s.w01 = (vy0 && vx1) ? (1.f - wy) * wx         : 0.f;
        s.w10 = (vy1 && vx0) ? wy * (1.f - wx)         : 0.f;
        s.w11 = (vy1 && vx1) ? wy * wx                 : 0.f;
        const int ch = g * 64 + kc * 8;
        s.v00 = *(const short8v*)(tb + (size_t)(y0c * WW + x0c) * CC + ch);
        s.v01 = *(const short8v*)(tb + (size_t)(y0c * WW + x1c) * CC + ch);
        s.v10 = *(const short8v*)(tb + (size_t)(y1c * WW + x0c) * CC + ch);
        s.v11 = *(const short8v*)(tb + (size_t)(y1c * WW + x1c) * CC + ch);
        return s;
    };
    // finish phase: bilinear blend + bf16 round + swizzled ds_write
    auto sampFinish = [&](const Samp& s, int buf) {
        short8v r;
#pragma unroll
        for (int e = 0; e < 8; e++) {
            float val = s.w00 * bf2f((unsigned short)s.v00[e]);
            val = fmaf(s.w01, bf2f((unsigned short)s.v01[e]), val);
            val = fmaf(s.w10, bf2f((unsigned short)s.v10[e]), val);
            val = fmaf(s.w11, bf2f((unsigned short)s.v11[e]), val);
            r[e] = (short)f2bf(val);
        }
        *(short8v*)&Bs[buf][xsw] = r;
    };
    auto mma = [&](int buf, const AF2& a) {
        {   // ks = 0, kchunk = quad
            const int kchunk = quad;
            const int row0 = r15, row1 = 16 + r15;
            short8v bf0 = *(const short8v*)&Bs[buf][(row0 * 8 + (kchunk ^ (row0 & 7))) * 8];
            short8v bf1 = *(const short8v*)&Bs[buf][(row1 * 8 + (kchunk ^ (row1 & 7))) * 8];
            acc[0][0] = __builtin_amdgcn_mfma_f32_16x16x32_bf16(a.c0i0, bf0, acc[0][0], 0, 0, 0);
            acc[0][1] = __builtin_amdgcn_mfma_f32_16x16x32_bf16(a.c0i0, bf1, acc[0][1], 0, 0, 0);
            acc[1][0] = __builtin_amdgcn_mfma_f32_16x16x32_bf16(a.c0i1, bf0, acc[1][0], 0, 0, 0);
            acc[1][1] = __builtin_amdgcn_mfma_f32_16x16x32_bf16(a.c0i1, bf1, acc[1][1], 0, 0, 0);
            acc[2][0] = __builtin_amdgcn_mfma_f32_16x16x32_bf16(a.c0i2, bf0, acc[2][0], 0, 0, 0);
            acc[2][1] = __builtin_amdgcn_mfma_f32_16x16x32_bf16(a.c0i2, bf1, acc[2][1], 0, 0, 0);
            acc[3][0] = __builtin_amdgcn_mfma_f32_16x16x32_bf16(a.c0i3, bf0, acc[3][0], 0, 0, 0);
            acc[3][1] = __builtin_amdgcn_mfma_f32_16x16x32_bf16(a.c0i3, bf1, acc[3][1], 0, 0, 0);
        }
        {   // ks = 1, kchunk = 4 + quad
            const int kchunk = 4 + quad;
            const int row0 = r15, row1 = 16 + r15;
            short8v bf0 = *(const short8v*)&Bs[buf][(row0 * 8 + (kchunk ^ (row0 & 7))) * 8];
            short8v bf1 = *(const short8v*)&Bs[buf][(row1 * 8 + (kchunk ^ (row1 & 7))) * 8];
            acc[0][0] = __builtin_amdgcn_mfma_f32_16x16x32_bf16(a.c1i0, bf0, acc[0][0], 0, 0, 0);
            acc[0][1] = __builtin_amdgcn_mfma_f32_16x16x32_bf16(a.c1i0, bf1, acc[0][1], 0, 0, 0);
            acc[1][0] = __builtin_amdgcn_mfma_f32_16x16x32_bf16(a.c1i1, bf0, acc[1][0], 0, 0, 0);
            acc[1][1] = __builtin_amdgcn_mfma_f32_16x16x32_bf16(a.c1i1, bf1, acc[1][1], 0, 0, 0);
            acc[2][0] = __builtin_amdgcn_mfma_f32_16x16x32_bf16(a.c1i2, bf0, acc[2][0], 0, 0, 0);
            acc[2][1] = __builtin_amdgcn_mfma_f32_16x16x32_bf16(a.c1i2, bf1, acc[2][1], 0, 0, 0);
            acc[3][0] = __builtin_amdgcn_mfma_f32_16x16x32_bf16(a.c1i3, bf0, acc[3][0], 0, 0, 0);
            acc[3][1] = __builtin_amdgcn_mfma_f32_16x16x32_bf16(a.c1i3, bf1, acc[3][1], 0, 0, 0);
        }
    };

    // ---- K-loop over all 36 kts (full-K), 2x-unrolled, named afA/afB ----
    AF2 afA = loadA(0), afB;
    { Samp s = sampIssue(0); sampFinish(s, 0); }
    __syncthreads();
    int cur = 0;
    for (int k2 = 0; k2 < (NKT - 2) / 2; k2++) {
        const int kt = 2 * k2;
        {   // step kt: consume afA, prefetch afB = A(kt+1)
            const int nxt = cur ^ 1;
            afB = loadA(kt + 1);
            Samp s = sampIssue(kt + 1);
            mma(cur, afA);
            sampFinish(s, nxt);
            __syncthreads();
            cur = nxt;
        }
        {   // step kt+1: consume afB, prefetch afA = A(kt+2)
            const int nxt = cur ^ 1;
            afA = loadA(kt + 2);
            Samp s = sampIssue(kt + 2);
            mma(cur, afB);
            sampFinish(s, nxt);
            __syncthreads();
            cur = nxt;
        }
    }
    {   // step NKT-2 = 34: consume afA, prefetch afB = A(35)
        const int nxt = cur ^ 1;
        afB = loadA(NKT - 1);
        Samp s = sampIssue(NKT - 1);
        mma(cur, afA);
        sampFinish(s, nxt);
        __syncthreads();
        cur = nxt;
    }
    mma(cur, afB);                              // step 35

    // ---- fused epilogue: relu + cls/bbox dots, cross-wave reduce ----
    float pc[2]  = {0.f, 0.f};
    float pb0[2] = {0.f, 0.f}, pb1[2] = {0.f, 0.f};
    float pb2[2] = {0.f, 0.f}, pb3[2] = {0.f, 0.f};
#pragma unroll
    for (int i = 0; i < 4; i++) {
        const int m = wm * 64 + i * 16 + quad * 4;
        const float4 cw  = *(const float4*)(cls_w + m);
        const float4 b0w = *(const float4*)(bbox_w + m);
        const float4 b1w = *(const float4*)(bbox_w + CC + m);
        const float4 b2w = *(const float4*)(bbox_w + 2 * CC + m);
        const float4 b3w = *(const float4*)(bbox_w + 3 * CC + m);
#pragma unroll
        for (int j = 0; j < 2; j++) {
            const float t0 = fmaxf(acc[i][j][0], 0.f);
            const float t1 = fmaxf(acc[i][j][1], 0.f);
            const float t2 = fmaxf(acc[i][j][2], 0.f);
            const float t3 = fmaxf(acc[i][j][3], 0.f);
            pc[j]  = fmaf(cw.x,  t0, fmaf(cw.y,  t1, fmaf(cw.z,  t2, fmaf(cw.w,  t3, pc[j]))));
            pb0[j] = fmaf(b0w.x, t0, fmaf(b0w.y, t1, fmaf(b0w.z, t2, fmaf(b0w.w, t3, pb0[j]))));
            pb1[j] = fmaf(b1w.x, t0, fmaf(b1w.y, t1, fmaf(b1w.z, t2, fmaf(b1w.w, t3, pb1[j]))));
            pb2[j] = fmaf(b2w.x, t0, fmaf(b2w.y, t1, fmaf(b2w.z, t2, fmaf(b2w.w, t3, pb2[j]))));
            pb3[j] = fmaf(b3w.x, t0, fmaf(b3w.y, t1, fmaf(b3w.z, t2, fmaf(b3w.w, t3, pb3[j]))));
        }
    }
    // reduce across quad (lanes r15 + 16*quad): xor 16, 32 sums all 4 quads
#pragma unroll
    for (int j = 0; j < 2; j++) {
#pragma unroll
        for (int off = 16; off <= 32; off <<= 1) {
            pc[j]  += __shfl_xor(pc[j],  off);
            pb0[j] += __shfl_xor(pb0[j], off);
            pb1[j] += __shfl_xor(pb1[j], off);
            pb2[j] += __shfl_xor(pb2[j], off);
            pb3[j] += __shfl_xor(pb3[j], off);
        }
    }
    if (quad == 0) {                            // lanes 0..15 hold reduced vals
#pragma unroll
        for (int j = 0; j < 2; j++) {
            const int nl = j * 16 + r15;
            sm[wm][nl][0] = pc[j];
            sm[wm][nl][1] = pb0[j];
            sm[wm][nl][2] = pb1[j];
            sm[wm][nl][3] = pb2[j];
            sm[wm][nl][4] = pb3[j];
        }
    }
    __syncthreads();
    if (tid < 32) {                             // one thread per pixel
        const int n = n0 + tid;
        const int bb = n / HWP, pp = n - bb * HWP;
        const float vc = sm[0][tid][0] + sm[1][tid][0] + sm[2][tid][0] + sm[3][tid][0];
        const float v0 = sm[0][tid][1] + sm[1][tid][1] + sm[2][tid][1] + sm[3][tid][1];
        const float v1 = sm[0][tid][2] + sm[1][tid][2] + sm[2][tid][2] + sm[3][tid][2];
        const float v2 = sm[0][tid][3] + sm[1][tid][3] + sm[2][tid][3] + sm[3][tid][3];
        const float v3 = sm[0][tid][4] + sm[1][tid][4] + sm[2][tid][4] + sm[3][tid][4];
        out[OUT_LOGITS + n] = vc + cls_b[0];
        out[OUT_BBOX + (bb * 4 + 0) * HWP + pp] = v0 + bbox_b[0];
        out[OUT_BBOX + (bb * 4 + 1) * HWP + pp] = v1 + bbox_b[1];
        out[OUT_BBOX + (bb * 4 + 2) * HWP + pp] = v2 + bbox_b[2];
        out[OUT_BBOX + (bb * 4 + 3) * HWP + pp] = v3 + bbox_b[3];
    }
}

// ----------------------------------------------------------------------------
extern "C" void kernel_launch(void* const* d_in, const int* in_sizes, int n_in,
                              void* d_out, int out_size, void* d_ws, size_t ws_size,
                              hipStream_t stream)
{
    const float* feature  = (const float*)d_in[0];
    const float* conv_w   = (const float*)d_in[1];
    const float* conv_b   = (const float*)d_in[2];
    const float* loc_w    = (const float*)d_in[3];
    const float* loc_b    = (const float*)d_in[4];
    const float* shape_w  = (const float*)d_in[5];
    const float* shape_b  = (const float*)d_in[6];
    const float* offset_w = (const float*)d_in[7];
    const float* adapt_w  = (const float*)d_in[8];
    const float* cls_w    = (const float*)d_in[9];
    const float* cls_b    = (const float*)d_in[10];
    const float* bbox_w   = (const float*)d_in[11];
    const float* bbox_b   = (const float*)d_in[12];
    float* out = (float*)d_out;

    // workspace partition (~23 MB)
    unsigned short* tcf  = (unsigned short*)d_ws;                  // NTOT*CC bf16
    unsigned short* fcf  = tcf + (size_t)NTOT * CC;                // NTOT*CC bf16
    unsigned short* W1p  = fcf + (size_t)NTOT * CC;                // CC*K1 bf16 (panels)
    unsigned short* W2p  = W1p + (size_t)CC * K1;                  // CC*K1 bf16 (panels)
    unsigned short* zp   = W2p + (size_t)CC * K1;                  // 1024 zeros
    float*          part = (float*)(zp + 1024);                    // NTOT x 6 fp32

    setup_kernel<<<dim3(PREP_BLOCKS + 1152), 256, 0, stream>>>(
        conv_w, adapt_w, feature, W1p, W2p, zp, fcf);
    gemm1_kernel<<<dim3(NTOT / 32 * 2), 256, 0, stream>>>(
        W1p, fcf, conv_b, zp, loc_w, shape_w, tcf, part);
    gemm2_fused_kernel<<<dim3(NTOT / 32), 256, 0, stream>>>(
        W2p, tcf, part, offset_w, loc_b, shape_b, cls_w, cls_b, bbox_w, bbox_b, out);
}